// Round 3
// baseline (287.797 us; speedup 1.0000x reference)
//
#include <hip/hip_runtime.h>
#include <hip/hip_bf16.h>
#include <cstdint>

#define B_    4
#define LQ    1024
#define LK    2048
#define FEAT  11
#define SP_   8
#define WD_   3
#define H_    8
#define HID_  256
#define LOG2E 1.4426950408889634f
#define SPLIT 2
#define KPS   (LK / SPLIT)    // 1024 k per split
#define ITERS (KPS / 64)      // 16 iterations of 64 k

typedef __attribute__((ext_vector_type(4))) float f32x4;
typedef __attribute__((ext_vector_type(8))) short bf16x8;
typedef __attribute__((ext_vector_type(4))) short s16x4;

__device__ __forceinline__ float sigmoidf_(float x) { return 1.f / (1.f + __expf(-x)); }

__device__ __forceinline__ short f2bf(float f) {
  unsigned u = __float_as_uint(f);
  u += 0x7fffu + ((u >> 16) & 1u);
  return (short)(u >> 16);
}

// ---------------------------------------------------------------------------
// Q projection -> Qh bf16 [bh][q][64]; scales (c1,c2) and log2e folded in.
// ---------------------------------------------------------------------------
__global__ __launch_bounds__(256) void proj_q_kernel(
    const float* __restrict__ q_fp, const float* __restrict__ Wq_s,
    const float* __restrict__ bq_s, const float* __restrict__ Wq_w,
    const float* __restrict__ bq_w, const float* __restrict__ wb,
    short* __restrict__ Qh)
{
  const int row = blockIdx.x;            // b*LQ + q
  const int t   = threadIdx.x;           // h*32 + d
  const float alpha = sigmoidf_(wb[0]);
  const float c1 = (1.f - alpha) * 0.17677669529663687f * LOG2E;
  const float c2 = 2.f * alpha * 10.f * LOG2E;

  const float* x = q_fp + (size_t)row * FEAT;
  float xs[FEAT];
  #pragma unroll
  for (int f = 0; f < FEAT; ++f) xs[f] = x[f];

  float s = bq_s[t];
  #pragma unroll
  for (int f = 0; f < SP_; ++f) s += xs[f] * Wq_s[t * SP_ + f];
  float w = bq_w[t];
  #pragma unroll
  for (int f = 0; f < WD_; ++f) w += xs[SP_ + f] * Wq_w[t * WD_ + f];

  const int h = t >> 5, d = t & 31;
  const int b = row >> 10, q = row & (LQ - 1);
  const size_t base = ((size_t)(b * H_ + h) * LQ + q) * 64;
  Qh[base + d]      = f2bf(c1 * s);
  Qh[base + 32 + d] = f2bf(c2 * w);
}

// ---------------------------------------------------------------------------
// K projection -> Kh bf16 [bh][k][64], Vp fp32 [bh][k][32],
// kb fp32 [bh][k] = -(alpha/TEMP)*log2e*||k_wp||^2
// ---------------------------------------------------------------------------
__global__ __launch_bounds__(256) void proj_k_kernel(
    const float* __restrict__ v_ret, const float* __restrict__ Wk_s,
    const float* __restrict__ bk_s, const float* __restrict__ Wk_w,
    const float* __restrict__ bk_w, const float* __restrict__ Wv,
    const float* __restrict__ bv,   const float* __restrict__ wb,
    short* __restrict__ Kh, float* __restrict__ Vp, float* __restrict__ kb)
{
  const int row = blockIdx.x;            // b*LK + k
  const int t   = threadIdx.x;
  const float alpha = sigmoidf_(wb[0]);

  const float* x = v_ret + (size_t)row * FEAT;
  float xs[FEAT];
  #pragma unroll
  for (int f = 0; f < FEAT; ++f) xs[f] = x[f];

  float s = bk_s[t];
  #pragma unroll
  for (int f = 0; f < SP_; ++f) s += xs[f] * Wk_s[t * SP_ + f];
  float w = bk_w[t];
  #pragma unroll
  for (int f = 0; f < WD_; ++f) w += xs[SP_ + f] * Wk_w[t * WD_ + f];
  float v = bv[t];
  #pragma unroll
  for (int f = 0; f < FEAT; ++f) v += xs[f] * Wv[t * FEAT + f];

  const int h = t >> 5, d = t & 31;
  const int b = row >> 11, k = row & (LK - 1);
  const size_t kcb = (size_t)(b * H_ + h) * LK + k;
  Kh[kcb * 64 + d]      = f2bf(s);
  Kh[kcb * 64 + 32 + d] = f2bf(w);
  Vp[kcb * 32 + d]      = v;

  float sq = w * w;
  #pragma unroll
  for (int off = 16; off >= 1; off >>= 1) sq += __shfl_down(sq, off, 32);
  if (d == 0) kb[kcb] = -10.f * alpha * LOG2E * sq;
}

// ---------------------------------------------------------------------------
// Transpose Vp [bh][k][32] fp32 -> Vt [bh][d][LK] bf16
// ---------------------------------------------------------------------------
__global__ __launch_bounds__(256) void vtrans_kernel(
    const float* __restrict__ Vp, short* __restrict__ Vt)
{
  __shared__ float lds[32][257];
  const int bh = blockIdx.y;
  const int k0 = blockIdx.x * 256;
  const int t  = threadIdx.x;

  const float* src = Vp + ((size_t)bh * LK + k0 + t) * 32;
  #pragma unroll
  for (int i = 0; i < 8; ++i) {
    f32x4 v = *(const f32x4*)(src + i * 4);
    lds[i * 4 + 0][t] = v[0]; lds[i * 4 + 1][t] = v[1];
    lds[i * 4 + 2][t] = v[2]; lds[i * 4 + 3][t] = v[3];
  }
  __syncthreads();

  const int d  = t >> 3;
  const int kc = (t & 7) * 32;
  short* dst = Vt + ((size_t)bh * 32 + d) * LK + k0 + kc;
  #pragma unroll
  for (int i = 0; i < 32; i += 4) {
    s16x4 hv;
    #pragma unroll
    for (int j = 0; j < 4; ++j) hv[j] = f2bf(lds[d][kc + i + j]);
    *(s16x4*)(dst + i) = hv;
  }
}

// ---------------------------------------------------------------------------
// Flash attention, split-K, 64-k iterations, MFMA.
// Wave = 16 q rows. Sub-tile k-row permutation makes S^T C-layout == PV
// B-layout (k = quad*8 + j), so softmax stays in registers.
// ---------------------------------------------------------------------------
union PF { int i[4]; bf16x8 v; };

__global__ __launch_bounds__(256, 4) void attn_kernel(
    const short* __restrict__ Qh, const short* __restrict__ Kh,
    const short* __restrict__ Vt, const float* __restrict__ kb,
    const float* __restrict__ pi, float* __restrict__ part)
{
  const int bh = blockIdx.y;
  const int sp = blockIdx.z;
  const int b = bh >> 3;
  const int wv = threadIdx.x >> 6;
  const int lane = threadIdx.x & 63;
  const int lo16 = lane & 15;
  const int quad = lane >> 4;
  const int q = blockIdx.x * 64 + wv * 16 + lo16;
  const int perm = ((lo16 >> 2) << 3) + (lo16 & 3);  // {0-3,8-11,16-19,24-27}
  const int k0 = sp * KPS;

  const size_t qoff = ((size_t)bh * LQ + q) * 64 + quad * 8;
  const bf16x8 qh0 = *(const bf16x8*)(Qh + qoff);
  const bf16x8 qh1 = *(const bf16x8*)(Qh + qoff + 32);

  const short* kbase  = Kh + ((size_t)bh * LK + k0 + perm) * 64 + quad * 8;
  const short* vbase  = Vt + ((size_t)bh * 32 + lo16) * LK + k0 + quad * 8;
  const float* pibase = pi + ((size_t)b * LQ + q) * LK + k0 + quad * 8;
  const float* kbbase = kb + (size_t)bh * LK + k0 + quad * 8;

  float m = -1e30f, l = 0.f;
  f32x4 o0 = {0.f, 0.f, 0.f, 0.f}, o1 = {0.f, 0.f, 0.f, 0.f};

  #pragma unroll 2
  for (int it = 0; it < ITERS; ++it) {
    // ---- loads for 64 k (subtile row offsets 0,4,32,36) ----
    const short* kp = kbase + it * (64 * 64);
    bf16x8 ka[4][2];
    ka[0][0] = *(const bf16x8*)(kp);              ka[0][1] = *(const bf16x8*)(kp + 32);
    ka[1][0] = *(const bf16x8*)(kp + 4  * 64);    ka[1][1] = *(const bf16x8*)(kp + 4  * 64 + 32);
    ka[2][0] = *(const bf16x8*)(kp + 32 * 64);    ka[2][1] = *(const bf16x8*)(kp + 32 * 64 + 32);
    ka[3][0] = *(const bf16x8*)(kp + 36 * 64);    ka[3][1] = *(const bf16x8*)(kp + 36 * 64 + 32);

    const short* vp = vbase + it * 64;
    bf16x8 va[2][2];  // [d-tile][k-window]
    va[0][0] = *(const bf16x8*)(vp);
    va[0][1] = *(const bf16x8*)(vp + 32);
    va[1][0] = *(const bf16x8*)(vp + 16 * LK);
    va[1][1] = *(const bf16x8*)(vp + 16 * LK + 32);

    const float* pp = pibase + it * 64;
    const float* bp = kbbase + it * 64;
    f32x4 pi4[4], kb4[4];
    pi4[0] = *(const f32x4*)(pp);      pi4[1] = *(const f32x4*)(pp + 4);
    pi4[2] = *(const f32x4*)(pp + 32); pi4[3] = *(const f32x4*)(pp + 36);
    kb4[0] = *(const f32x4*)(bp);      kb4[1] = *(const f32x4*)(bp + 4);
    kb4[2] = *(const f32x4*)(bp + 32); kb4[3] = *(const f32x4*)(bp + 36);

    // ---- QK^T (S^T, 4 subtiles) ----
    f32x4 st[4];
    #pragma unroll
    for (int t4 = 0; t4 < 4; ++t4) {
      f32x4 z = {0.f, 0.f, 0.f, 0.f};
      z = __builtin_amdgcn_mfma_f32_16x16x32_bf16(ka[t4][0], qh0, z, 0, 0, 0);
      z = __builtin_amdgcn_mfma_f32_16x16x32_bf16(ka[t4][1], qh1, z, 0, 0, 0);
      st[t4] = z;
    }

    // ---- logits (log2 domain), lane value [t4][r] -> k = quad*8 + off(t4) + r
    float lg[16];
    #pragma unroll
    for (int t4 = 0; t4 < 4; ++t4) {
      #pragma unroll
      for (int r = 0; r < 4; ++r)
        lg[t4 * 4 + r] = st[t4][r] + kb4[t4][r]
                         + __builtin_amdgcn_logf(fmaxf(pi4[t4][r], 1e-9f));
    }

    float cm = lg[0];
    #pragma unroll
    for (int j = 1; j < 16; ++j) cm = fmaxf(cm, lg[j]);
    cm = fmaxf(cm, __shfl_xor(cm, 16));
    cm = fmaxf(cm, __shfl_xor(cm, 32));
    const float mn = fmaxf(m, cm);
    const float sc = __builtin_amdgcn_exp2f(m - mn);

    // ---- p = exp2(lg - mn), truncation-pack to bf16 via v_perm ----
    unsigned eu[16];
    #pragma unroll
    for (int j = 0; j < 16; ++j)
      eu[j] = __float_as_uint(__builtin_amdgcn_exp2f(lg[j] - mn));

    PF pf0, pf1;
    float ps = 0.f;
    #pragma unroll
    for (int p = 0; p < 4; ++p) {
      const int w0 = __builtin_amdgcn_perm(eu[2 * p + 1], eu[2 * p], 0x07060302u);
      const int w1 = __builtin_amdgcn_perm(eu[8 + 2 * p + 1], eu[8 + 2 * p], 0x07060302u);
      pf0.i[p] = w0; pf1.i[p] = w1;
      ps += __uint_as_float(((unsigned)w0) << 16) + __uint_as_float(w0 & 0xffff0000u);
      ps += __uint_as_float(((unsigned)w1) << 16) + __uint_as_float(w1 & 0xffff0000u);
    }
    ps += __shfl_xor(ps, 16);
    ps += __shfl_xor(ps, 32);
    l = l * sc + ps;
    m = mn;
    #pragma unroll
    for (int r = 0; r < 4; ++r) { o0[r] *= sc; o1[r] *= sc; }

    // ---- PV ----
    o0 = __builtin_amdgcn_mfma_f32_16x16x32_bf16(va[0][0], pf0.v, o0, 0, 0, 0);
    o0 = __builtin_amdgcn_mfma_f32_16x16x32_bf16(va[0][1], pf1.v, o0, 0, 0, 0);
    o1 = __builtin_amdgcn_mfma_f32_16x16x32_bf16(va[1][0], pf0.v, o1, 0, 0, 0);
    o1 = __builtin_amdgcn_mfma_f32_16x16x32_bf16(va[1][1], pf1.v, o1, 0, 0, 0);
  }

  // ---- partial out: [sp][bh][q] stride 36 floats: m, l, _, _, o[32]
  float* ppart = part + ((size_t)(sp * 32 + bh) * LQ + q) * 36;
  if (quad == 0) { ppart[0] = m; ppart[1] = l; }
  *(f32x4*)(ppart + 4 + quad * 4)  = o0;
  *(f32x4*)(ppart + 20 + quad * 4) = o1;
}

// ---------------------------------------------------------------------------
// Merge SPLIT partials -> ctx (B, LQ, 256) in (h*32+d) layout
// ---------------------------------------------------------------------------
__global__ __launch_bounds__(256) void combine_kernel(
    const float* __restrict__ part, float* __restrict__ ctx)
{
  const int g = blockIdx.x * 256 + threadIdx.x;   // (bh*LQ+q)*32 + d
  const int r = g >> 5;
  const int d = g & 31;
  const int bh = r >> 10, qq = r & (LQ - 1);
  const int b = bh >> 3, h = bh & 7;

  const float* p0 = part + (size_t)r * 36;
  const float* p1 = part + (size_t)(B_ * H_ * LQ + r) * 36;
  const float m0 = p0[0], l0 = p0[1], m1 = p1[0], l1 = p1[1];
  const float mM = fmaxf(m0, m1);
  const float w0 = __builtin_amdgcn_exp2f(m0 - mM);
  const float w1 = __builtin_amdgcn_exp2f(m1 - mM);
  const float num = w0 * p0[4 + d] + w1 * p1[4 + d];
  const float den = w0 * l0 + w1 * l1;
  ctx[((size_t)(b * LQ + qq)) * HID_ + h * 32 + d] = num / den;
}

// ---------------------------------------------------------------------------
// out = ctx @ Wo^T + bo.  256 blocks of 16 rows; thread: 4 rows x 4 cols.
// ---------------------------------------------------------------------------
__global__ __launch_bounds__(256) void out_kernel(
    const float* __restrict__ ctx, const float* __restrict__ Wo,
    const float* __restrict__ bo, float* __restrict__ out)
{
  __shared__ float cs[16 * 256];
  const int t = threadIdx.x;
  const size_t r0 = (size_t)blockIdx.x * 16;

  const f32x4* src = reinterpret_cast<const f32x4*>(ctx + r0 * HID_);
  f32x4* dst = reinterpret_cast<f32x4*>(cs);
  #pragma unroll
  for (int i = 0; i < 4; ++i) dst[i * 256 + t] = src[i * 256 + t];
  __syncthreads();

  const int o0 = (t & 63) * 4;
  const int rs = (t >> 6) * 4;
  float acc[4][4];
  #pragma unroll
  for (int r = 0; r < 4; ++r) {
    #pragma unroll
    for (int j = 0; j < 4; ++j) acc[r][j] = bo[o0 + j];
  }

  for (int c4 = 0; c4 < 64; ++c4) {
    const f32x4 w0 = *(const f32x4*)(Wo + (size_t)(o0 + 0) * HID_ + c4 * 4);
    const f32x4 w1 = *(const f32x4*)(Wo + (size_t)(o0 + 1) * HID_ + c4 * 4);
    const f32x4 w2 = *(const f32x4*)(Wo + (size_t)(o0 + 2) * HID_ + c4 * 4);
    const f32x4 w3 = *(const f32x4*)(Wo + (size_t)(o0 + 3) * HID_ + c4 * 4);
    #pragma unroll
    for (int r = 0; r < 4; ++r) {
      const f32x4 cv = *(const f32x4*)(cs + (rs + r) * 256 + c4 * 4);
      acc[r][0] += cv[0] * w0[0] + cv[1] * w0[1] + cv[2] * w0[2] + cv[3] * w0[3];
      acc[r][1] += cv[0] * w1[0] + cv[1] * w1[1] + cv[2] * w1[2] + cv[3] * w1[3];
      acc[r][2] += cv[0] * w2[0] + cv[1] * w2[1] + cv[2] * w2[2] + cv[3] * w2[3];
      acc[r][3] += cv[0] * w3[0] + cv[1] * w3[1] + cv[2] * w3[2] + cv[3] * w3[3];
    }
  }
  #pragma unroll
  for (int r = 0; r < 4; ++r) {
    f32x4 res;
    res[0] = acc[r][0]; res[1] = acc[r][1]; res[2] = acc[r][2]; res[3] = acc[r][3];
    *(f32x4*)(out + (r0 + rs + r) * HID_ + o0) = res;
  }
}

// ---------------------------------------------------------------------------
extern "C" void kernel_launch(void* const* d_in, const int* in_sizes, int n_in,
                              void* d_out, int out_size, void* d_ws, size_t ws_size,
                              hipStream_t stream)
{
  const float* q_fp  = (const float*)d_in[0];
  const float* v_ret = (const float*)d_in[1];
  const float* pi    = (const float*)d_in[2];
  const float* Wq_s  = (const float*)d_in[3];
  const float* bq_s  = (const float*)d_in[4];
  const float* Wk_s  = (const float*)d_in[5];
  const float* bk_s  = (const float*)d_in[6];
  const float* Wq_w  = (const float*)d_in[7];
  const float* bq_w  = (const float*)d_in[8];
  const float* Wk_w  = (const float*)d_in[9];
  const float* bk_w  = (const float*)d_in[10];
  const float* Wv    = (const float*)d_in[11];
  const float* bv    = (const float*)d_in[12];
  const float* Wo    = (const float*)d_in[13];
  const float* bo    = (const float*)d_in[14];
  const float* wb    = (const float*)d_in[15];
  float* out = (float*)d_out;

  // ws layout (bytes): Qh 4M | Kh 8M | Vt 4M | kb 256K | ctx 4M | Vp/part 9.44M
  short* Qh = (short*)d_ws;                               // 2,097,152 sh
  short* Kh = Qh + (size_t)2097152;                       // 4,194,304 sh
  short* Vt = Kh + (size_t)4194304;                       // 2,097,152 sh
  float* kbuf = (float*)(Vt + (size_t)2097152);           //    65,536 fl
  float* ctx  = kbuf + (size_t)65536;                     // 1,048,576 fl
  float* Vp   = ctx + (size_t)1048576;                    // 2,097,152 fl (reused)
  float* part = Vp;                                       // 2,359,296 fl (after vtrans)

  proj_q_kernel<<<B_ * LQ, 256, 0, stream>>>(q_fp, Wq_s, bq_s, Wq_w, bq_w, wb, Qh);
  proj_k_kernel<<<B_ * LK, 256, 0, stream>>>(v_ret, Wk_s, bk_s, Wk_w, bk_w, Wv, bv, wb,
                                             Kh, Vp, kbuf);
  vtrans_kernel<<<dim3(LK / 256, 32), 256, 0, stream>>>(Vp, Vt);
  attn_kernel<<<dim3(LQ / 64, 32, SPLIT), 256, 0, stream>>>(Qh, Kh, Vt, kbuf, pi, part);
  combine_kernel<<<(B_ * H_ * LQ * 32) / 256, 256, 0, stream>>>(part, ctx);
  out_kernel<<<(B_ * LQ) / 16, 256, 0, stream>>>(ctx, Wo, bo, out);
}

// Round 4
// 215.476 us; speedup vs baseline: 1.3356x; 1.3356x over previous
//
#include <hip/hip_runtime.h>
#include <hip/hip_bf16.h>
#include <cstdint>

#define B_    4
#define LQ    1024
#define LK    2048
#define FEAT  11
#define SP_   8
#define WD_   3
#define H_    8
#define HID_  256
#define LOG2E 1.4426950408889634f
#define SPLIT 2
#define KPS   (LK / SPLIT)    // 1024 k per split
#define ITERS (KPS / 64)      // 16 iterations of 64 k

typedef __attribute__((ext_vector_type(4))) float f32x4;
typedef __attribute__((ext_vector_type(8))) short bf16x8;

__device__ __forceinline__ float sigmoidf_(float x) { return 1.f / (1.f + __expf(-x)); }

__device__ __forceinline__ short f2bf(float f) {
  unsigned u = __float_as_uint(f);
  u += 0x7fffu + ((u >> 16) & 1u);
  return (short)(u >> 16);
}

__device__ __forceinline__ void gl_lds16(const void* g, void* l) {
  __builtin_amdgcn_global_load_lds(
      (const __attribute__((address_space(1))) unsigned int*)g,
      (__attribute__((address_space(3))) unsigned int*)l, 16, 0, 0);
}

// ---------------------------------------------------------------------------
// Q projection -> Qh bf16 [bh][q][64]; scales (c1,c2) and log2e folded in.
// ---------------------------------------------------------------------------
__global__ __launch_bounds__(256) void proj_q_kernel(
    const float* __restrict__ q_fp, const float* __restrict__ Wq_s,
    const float* __restrict__ bq_s, const float* __restrict__ Wq_w,
    const float* __restrict__ bq_w, const float* __restrict__ wb,
    short* __restrict__ Qh)
{
  const int row = blockIdx.x;            // b*LQ + q
  const int t   = threadIdx.x;           // h*32 + d
  const float alpha = sigmoidf_(wb[0]);
  const float c1 = (1.f - alpha) * 0.17677669529663687f * LOG2E;
  const float c2 = 2.f * alpha * 10.f * LOG2E;

  const float* x = q_fp + (size_t)row * FEAT;
  float xs[FEAT];
  #pragma unroll
  for (int f = 0; f < FEAT; ++f) xs[f] = x[f];

  float s = bq_s[t];
  #pragma unroll
  for (int f = 0; f < SP_; ++f) s += xs[f] * Wq_s[t * SP_ + f];
  float w = bq_w[t];
  #pragma unroll
  for (int f = 0; f < WD_; ++f) w += xs[SP_ + f] * Wq_w[t * WD_ + f];

  const int h = t >> 5, d = t & 31;
  const int b = row >> 10, q = row & (LQ - 1);
  const size_t base = ((size_t)(b * H_ + h) * LQ + q) * 64;
  Qh[base + d]      = f2bf(c1 * s);
  Qh[base + 32 + d] = f2bf(c2 * w);
}

// ---------------------------------------------------------------------------
// K projection -> Kh bf16 [bh][k][64], Vp fp32 [bh][k][32],
// kb fp32 [bh][k] = -(alpha/TEMP)*log2e*||k_wp||^2
// ---------------------------------------------------------------------------
__global__ __launch_bounds__(256) void proj_k_kernel(
    const float* __restrict__ v_ret, const float* __restrict__ Wk_s,
    const float* __restrict__ bk_s, const float* __restrict__ Wk_w,
    const float* __restrict__ bk_w, const float* __restrict__ Wv,
    const float* __restrict__ bv,   const float* __restrict__ wb,
    short* __restrict__ Kh, float* __restrict__ Vp, float* __restrict__ kb)
{
  const int row = blockIdx.x;            // b*LK + k
  const int t   = threadIdx.x;
  const float alpha = sigmoidf_(wb[0]);

  const float* x = v_ret + (size_t)row * FEAT;
  float xs[FEAT];
  #pragma unroll
  for (int f = 0; f < FEAT; ++f) xs[f] = x[f];

  float s = bk_s[t];
  #pragma unroll
  for (int f = 0; f < SP_; ++f) s += xs[f] * Wk_s[t * SP_ + f];
  float w = bk_w[t];
  #pragma unroll
  for (int f = 0; f < WD_; ++f) w += xs[SP_ + f] * Wk_w[t * WD_ + f];
  float v = bv[t];
  #pragma unroll
  for (int f = 0; f < FEAT; ++f) v += xs[f] * Wv[t * FEAT + f];

  const int h = t >> 5, d = t & 31;
  const int b = row >> 11, k = row & (LK - 1);
  const size_t kcb = (size_t)(b * H_ + h) * LK + k;
  Kh[kcb * 64 + d]      = f2bf(s);
  Kh[kcb * 64 + 32 + d] = f2bf(w);
  Vp[kcb * 32 + d]      = v;

  float sq = w * w;
  #pragma unroll
  for (int off = 16; off >= 1; off >>= 1) sq += __shfl_down(sq, off, 32);
  if (d == 0) kb[kcb] = -10.f * alpha * LOG2E * sq;
}

// ---------------------------------------------------------------------------
// Prepack: build KV[bh][blk][768] 16B-granules:
//   granules 0..511  : K fragments, granule (j=t4*2+half)*64+lane holds
//                      Kh[k = blk*64 + off(t4)+perm(lane&15)][(lane>>4)*8 + half*32 ..8]
//   granules 512..767: V fragments, granule 512+(j=dt*2+kw)*64+lane holds
//                      V^T[d = dt*16+(lane&15)][k = blk*64 + kw*32 + (lane>>4)*8 ..8]
// One block per (blk, bh).
// ---------------------------------------------------------------------------
__global__ __launch_bounds__(256) void prepack_kernel(
    const short* __restrict__ Kh, const float* __restrict__ Vp,
    short* __restrict__ KV)
{
  __shared__ float ldsv[64][33];
  const int blk = blockIdx.x, bh = blockIdx.y;
  const int t = threadIdx.x;

  // stage V tile [64 k][32 d] into LDS
  {
    const int row = t >> 2, part = t & 3;
    const float* src = Vp + ((size_t)bh * LK + blk * 64 + row) * 32 + part * 8;
    f32x4 a = *(const f32x4*)(src);
    f32x4 b = *(const f32x4*)(src + 4);
    #pragma unroll
    for (int i = 0; i < 4; ++i) { ldsv[row][part * 8 + i] = a[i]; ldsv[row][part * 8 + 4 + i] = b[i]; }
  }

  // K granules (no LDS dependency)
  const size_t base = ((size_t)bh * 32 + blk) * 768;
  #pragma unroll
  for (int gs = 0; gs < 2; ++gs) {
    const int g = gs * 256 + t;
    const int j = g >> 6, lane = g & 63;
    const int t4 = j >> 1, half = j & 1;
    const int quad = lane >> 4, lo = lane & 15;
    const int off = ((t4 >> 1) << 5) + ((t4 & 1) << 2);       // {0,4,32,36}
    const int kk = blk * 64 + off + ((lo >> 2) << 3) + (lo & 3);
    bf16x8 v = *(const bf16x8*)(Kh + ((size_t)bh * LK + kk) * 64 + quad * 8 + half * 32);
    *(bf16x8*)(KV + (base + g) * 8) = v;
  }

  __syncthreads();

  // V granules
  {
    const int g = t;
    const int j = g >> 6, lane = g & 63;
    const int dt = j >> 1, kw = j & 1;
    const int quad = lane >> 4, lo = lane & 15;
    bf16x8 hv;
    #pragma unroll
    for (int i = 0; i < 8; ++i)
      hv[i] = f2bf(ldsv[kw * 32 + quad * 8 + i][dt * 16 + lo]);
    *(bf16x8*)(KV + (base + 512 + g) * 8) = hv;
  }
}

// ---------------------------------------------------------------------------
// Flash attention: LDS-staged K/V (double buffer, global_load_lds), MFMA,
// log-free softmax: p = pi * exp2(s + kb - m).
// ---------------------------------------------------------------------------
union PF { int i[4]; bf16x8 v; };

__global__ __launch_bounds__(256, 4) void attn_kernel(
    const short* __restrict__ Qh, const short* __restrict__ KV,
    const float* __restrict__ kb, const float* __restrict__ pi,
    float* __restrict__ part)
{
  __shared__ short skv[2][6144];   // 2 x 768 granules x 16 B
  const int bh = blockIdx.y;
  const int sp = blockIdx.z;
  const int b = bh >> 3;
  const int wv = threadIdx.x >> 6;
  const int lane = threadIdx.x & 63;
  const int lo16 = lane & 15;
  const int quad = lane >> 4;
  const int q = blockIdx.x * 64 + wv * 16 + lo16;
  const int k0 = sp * KPS;
  const int blk0 = sp * 16;

  const size_t qoff = ((size_t)bh * LQ + q) * 64 + quad * 8;
  const bf16x8 qh0 = *(const bf16x8*)(Qh + qoff);
  const bf16x8 qh1 = *(const bf16x8*)(Qh + qoff + 32);

  const float* pibase = pi + ((size_t)b * LQ + q) * LK + k0 + quad * 8;
  const float* kbbase = kb + (size_t)bh * LK + k0 + quad * 8;

  float m = -1e30f, l = 0.f;
  f32x4 o0 = {0.f, 0.f, 0.f, 0.f}, o1 = {0.f, 0.f, 0.f, 0.f};

  // prologue stage into buffer 0
  {
    const size_t gb = ((size_t)bh * 32 + blk0) * 768;
    #pragma unroll
    for (int c = 0; c < 3; ++c)
      gl_lds16(KV + (gb + c * 256 + wv * 64 + lane) * 8,
               &skv[0][c * 2048 + wv * 512]);
  }

  #pragma unroll 2
  for (int it = 0; it < ITERS; ++it) {
    __syncthreads();   // drains previous stage; buffer (it&1) ready
    if (it + 1 < ITERS) {
      const size_t gb = ((size_t)bh * 32 + blk0 + it + 1) * 768;
      short* db = skv[(it + 1) & 1];
      #pragma unroll
      for (int c = 0; c < 3; ++c)
        gl_lds16(KV + (gb + c * 256 + wv * 64 + lane) * 8,
                 db + c * 2048 + wv * 512);
    }
    const short* cbuf = skv[it & 1];

    // pi / kb loads (per-lane global; issued early)
    const float* pp = pibase + it * 64;
    const float* bp = kbbase + it * 64;
    f32x4 pi4[4], kb4[4];
    pi4[0] = *(const f32x4*)(pp);      pi4[1] = *(const f32x4*)(pp + 4);
    pi4[2] = *(const f32x4*)(pp + 32); pi4[3] = *(const f32x4*)(pp + 36);
    kb4[0] = *(const f32x4*)(bp);      kb4[1] = *(const f32x4*)(bp + 4);
    kb4[2] = *(const f32x4*)(bp + 32); kb4[3] = *(const f32x4*)(bp + 36);

    // QK^T from LDS fragments (lane-linear, conflict-free)
    f32x4 st[4];
    #pragma unroll
    for (int t4 = 0; t4 < 4; ++t4) {
      const bf16x8 ka0 = *(const bf16x8*)(cbuf + ((t4 * 2 + 0) * 64 + lane) * 8);
      const bf16x8 ka1 = *(const bf16x8*)(cbuf + ((t4 * 2 + 1) * 64 + lane) * 8);
      f32x4 z = {0.f, 0.f, 0.f, 0.f};
      z = __builtin_amdgcn_mfma_f32_16x16x32_bf16(ka0, qh0, z, 0, 0, 0);
      z = __builtin_amdgcn_mfma_f32_16x16x32_bf16(ka1, qh1, z, 0, 0, 0);
      st[t4] = z;
    }

    // logits = s + kb (log2-domain); pi multiplied after exp2 (no log!)
    float lg[16];
    #pragma unroll
    for (int t4 = 0; t4 < 4; ++t4) {
      #pragma unroll
      for (int r = 0; r < 4; ++r) lg[t4 * 4 + r] = st[t4][r] + kb4[t4][r];
    }

    float cm = lg[0];
    #pragma unroll
    for (int j = 1; j < 16; ++j) cm = fmaxf(cm, lg[j]);
    cm = fmaxf(cm, __shfl_xor(cm, 16));
    cm = fmaxf(cm, __shfl_xor(cm, 32));
    const float mn = fmaxf(m, cm);
    const float sc = __builtin_amdgcn_exp2f(m - mn);

    unsigned eu[16];
    #pragma unroll
    for (int t4 = 0; t4 < 4; ++t4) {
      #pragma unroll
      for (int r = 0; r < 4; ++r)
        eu[t4 * 4 + r] = __float_as_uint(
            __builtin_amdgcn_exp2f(lg[t4 * 4 + r] - mn) * fmaxf(pi4[t4][r], 1e-9f));
    }

    PF pf0, pf1;
    float ps = 0.f;
    #pragma unroll
    for (int p = 0; p < 4; ++p) {
      const int w0 = __builtin_amdgcn_perm(eu[2 * p + 1], eu[2 * p], 0x07060302u);
      const int w1 = __builtin_amdgcn_perm(eu[8 + 2 * p + 1], eu[8 + 2 * p], 0x07060302u);
      pf0.i[p] = w0; pf1.i[p] = w1;
      ps += __uint_as_float(((unsigned)w0) << 16) + __uint_as_float(w0 & 0xffff0000u);
      ps += __uint_as_float(((unsigned)w1) << 16) + __uint_as_float(w1 & 0xffff0000u);
    }
    ps += __shfl_xor(ps, 16);
    ps += __shfl_xor(ps, 32);
    l = l * sc + ps;
    m = mn;
    #pragma unroll
    for (int r = 0; r < 4; ++r) { o0[r] *= sc; o1[r] *= sc; }

    // PV from LDS V fragments
    const bf16x8 va00 = *(const bf16x8*)(cbuf + ((512 + 0 * 64) + lane) * 8);
    const bf16x8 va01 = *(const bf16x8*)(cbuf + ((512 + 1 * 64) + lane) * 8);
    const bf16x8 va10 = *(const bf16x8*)(cbuf + ((512 + 2 * 64) + lane) * 8);
    const bf16x8 va11 = *(const bf16x8*)(cbuf + ((512 + 3 * 64) + lane) * 8);
    o0 = __builtin_amdgcn_mfma_f32_16x16x32_bf16(va00, pf0.v, o0, 0, 0, 0);
    o0 = __builtin_amdgcn_mfma_f32_16x16x32_bf16(va01, pf1.v, o0, 0, 0, 0);
    o1 = __builtin_amdgcn_mfma_f32_16x16x32_bf16(va10, pf0.v, o1, 0, 0, 0);
    o1 = __builtin_amdgcn_mfma_f32_16x16x32_bf16(va11, pf1.v, o1, 0, 0, 0);
  }

  // partial out: [sp][bh][q] stride 36 floats: m, l, _, _, o[32]
  float* ppart = part + ((size_t)(sp * 32 + bh) * LQ + q) * 36;
  if (quad == 0) { ppart[0] = m; ppart[1] = l; }
  *(f32x4*)(ppart + 4 + quad * 4)  = o0;
  *(f32x4*)(ppart + 20 + quad * 4) = o1;
}

// ---------------------------------------------------------------------------
// Merge SPLIT partials -> ctx (B, LQ, 256) in (h*32+d) layout
// ---------------------------------------------------------------------------
__global__ __launch_bounds__(256) void combine_kernel(
    const float* __restrict__ part, float* __restrict__ ctx)
{
  const int g = blockIdx.x * 256 + threadIdx.x;   // (bh*LQ+q)*32 + d
  const int r = g >> 5;
  const int d = g & 31;
  const int bh = r >> 10, qq = r & (LQ - 1);
  const int b = bh >> 3, h = bh & 7;

  const float* p0 = part + (size_t)r * 36;
  const float* p1 = part + (size_t)(B_ * H_ * LQ + r) * 36;
  const float m0 = p0[0], l0 = p0[1], m1 = p1[0], l1 = p1[1];
  const float mM = fmaxf(m0, m1);
  const float w0 = __builtin_amdgcn_exp2f(m0 - mM);
  const float w1 = __builtin_amdgcn_exp2f(m1 - mM);
  const float num = w0 * p0[4 + d] + w1 * p1[4 + d];
  const float den = w0 * l0 + w1 * l1;
  ctx[((size_t)(b * LQ + qq)) * HID_ + h * 32 + d] = num / den;
}

// ---------------------------------------------------------------------------
// out = ctx @ Wo^T + bo.  256 blocks of 16 rows; thread: 4 rows x 4 cols.
// ---------------------------------------------------------------------------
__global__ __launch_bounds__(256) void out_kernel(
    const float* __restrict__ ctx, const float* __restrict__ Wo,
    const float* __restrict__ bo, float* __restrict__ out)
{
  __shared__ float cs[16 * 256];
  const int t = threadIdx.x;
  const size_t r0 = (size_t)blockIdx.x * 16;

  const f32x4* src = reinterpret_cast<const f32x4*>(ctx + r0 * HID_);
  f32x4* dst = reinterpret_cast<f32x4*>(cs);
  #pragma unroll
  for (int i = 0; i < 4; ++i) dst[i * 256 + t] = src[i * 256 + t];
  __syncthreads();

  const int o0 = (t & 63) * 4;
  const int rs = (t >> 6) * 4;
  float acc[4][4];
  #pragma unroll
  for (int r = 0; r < 4; ++r) {
    #pragma unroll
    for (int j = 0; j < 4; ++j) acc[r][j] = bo[o0 + j];
  }

  for (int c4 = 0; c4 < 64; ++c4) {
    const f32x4 w0 = *(const f32x4*)(Wo + (size_t)(o0 + 0) * HID_ + c4 * 4);
    const f32x4 w1 = *(const f32x4*)(Wo + (size_t)(o0 + 1) * HID_ + c4 * 4);
    const f32x4 w2 = *(const f32x4*)(Wo + (size_t)(o0 + 2) * HID_ + c4 * 4);
    const f32x4 w3 = *(const f32x4*)(Wo + (size_t)(o0 + 3) * HID_ + c4 * 4);
    #pragma unroll
    for (int r = 0; r < 4; ++r) {
      const f32x4 cv = *(const f32x4*)(cs + (rs + r) * 256 + c4 * 4);
      acc[r][0] += cv[0] * w0[0] + cv[1] * w0[1] + cv[2] * w0[2] + cv[3] * w0[3];
      acc[r][1] += cv[0] * w1[0] + cv[1] * w1[1] + cv[2] * w1[2] + cv[3] * w1[3];
      acc[r][2] += cv[0] * w2[0] + cv[1] * w2[1] + cv[2] * w2[2] + cv[3] * w2[3];
      acc[r][3] += cv[0] * w3[0] + cv[1] * w3[1] + cv[2] * w3[2] + cv[3] * w3[3];
    }
  }
  #pragma unroll
  for (int r = 0; r < 4; ++r) {
    f32x4 res;
    res[0] = acc[r][0]; res[1] = acc[r][1]; res[2] = acc[r][2]; res[3] = acc[r][3];
    *(f32x4*)(out + (r0 + rs + r) * HID_ + o0) = res;
  }
}

// ---------------------------------------------------------------------------
extern "C" void kernel_launch(void* const* d_in, const int* in_sizes, int n_in,
                              void* d_out, int out_size, void* d_ws, size_t ws_size,
                              hipStream_t stream)
{
  const float* q_fp  = (const float*)d_in[0];
  const float* v_ret = (const float*)d_in[1];
  const float* pi    = (const float*)d_in[2];
  const float* Wq_s  = (const float*)d_in[3];
  const float* bq_s  = (const float*)d_in[4];
  const float* Wk_s  = (const float*)d_in[5];
  const float* bk_s  = (const float*)d_in[6];
  const float* Wq_w  = (const float*)d_in[7];
  const float* bq_w  = (const float*)d_in[8];
  const float* Wk_w  = (const float*)d_in[9];
  const float* bk_w  = (const float*)d_in[10];
  const float* Wv    = (const float*)d_in[11];
  const float* bv    = (const float*)d_in[12];
  const float* Wo    = (const float*)d_in[13];
  const float* bo    = (const float*)d_in[14];
  const float* wb    = (const float*)d_in[15];
  float* out = (float*)d_out;

  short* Qh   = (short*)d_ws;                     // 2,097,152 sh  (4 MB)
  short* KV   = Qh + (size_t)2097152;             // 6,291,456 sh  (12 MB)
  float* kbuf = (float*)(KV + (size_t)6291456);   //    65,536 fl
  float* ctx  = kbuf + (size_t)65536;             // 1,048,576 fl  (4 MB)
  short* Kh   = (short*)(ctx + (size_t)1048576);  // 4,194,304 sh  (8 MB, temp)
  float* Vp   = (float*)(Kh + (size_t)4194304);   // 2,097,152 fl  (8 MB, temp)
  float* part = (float*)Kh;                       // alias: used after prepack

  proj_q_kernel<<<B_ * LQ, 256, 0, stream>>>(q_fp, Wq_s, bq_s, Wq_w, bq_w, wb, Qh);
  proj_k_kernel<<<B_ * LK, 256, 0, stream>>>(v_ret, Wk_s, bk_s, Wk_w, bk_w, Wv, bv, wb,
                                             Kh, Vp, kbuf);
  prepack_kernel<<<dim3(LK / 64, 32), 256, 0, stream>>>(Kh, Vp, KV);
  attn_kernel<<<dim3(LQ / 64, 32, SPLIT), 256, 0, stream>>>(Qh, KV, kbuf, pi, part);
  combine_kernel<<<(B_ * H_ * LQ * 32) / 256, 256, 0, stream>>>(part, ctx);
  out_kernel<<<(B_ * LQ) / 16, 256, 0, stream>>>(ctx, Wo, bo, out);
}

// Round 5
// 205.248 us; speedup vs baseline: 1.4022x; 1.0498x over previous
//
#include <hip/hip_runtime.h>
#include <hip/hip_bf16.h>
#include <cstdint>

#define B_    4
#define LQ    1024
#define LK    2048
#define FEAT  11
#define SP_   8
#define WD_   3
#define H_    8
#define HID_  256
#define LOG2E 1.4426950408889634f
#define SPLIT 2
#define KPS   (LK / SPLIT)    // 1024 k per split
#define ITERS (KPS / 64)      // 16 iterations of 64 k

typedef __attribute__((ext_vector_type(4))) float f32x4;
typedef __attribute__((ext_vector_type(8))) short bf16x8;

__device__ __forceinline__ float sigmoidf_(float x) { return 1.f / (1.f + __expf(-x)); }

__device__ __forceinline__ short f2bf(float f) {
  unsigned u = __float_as_uint(f);
  u += 0x7fffu + ((u >> 16) & 1u);
  return (short)(u >> 16);
}

__device__ __forceinline__ void gl_lds16(const void* g, void* l) {
  __builtin_amdgcn_global_load_lds(
      (const __attribute__((address_space(1))) unsigned int*)g,
      (__attribute__((address_space(3))) unsigned int*)l, 16, 0, 0);
}

// ---------------------------------------------------------------------------
// Q projection -> Qh bf16 [bh][q][64]; scales (c1,c2) and log2e folded in.
// ---------------------------------------------------------------------------
__global__ __launch_bounds__(256) void proj_q_kernel(
    const float* __restrict__ q_fp, const float* __restrict__ Wq_s,
    const float* __restrict__ bq_s, const float* __restrict__ Wq_w,
    const float* __restrict__ bq_w, const float* __restrict__ wb,
    short* __restrict__ Qh)
{
  const int row = blockIdx.x;            // b*LQ + q
  const int t   = threadIdx.x;           // h*32 + d
  const float alpha = sigmoidf_(wb[0]);
  const float c1 = (1.f - alpha) * 0.17677669529663687f * LOG2E;
  const float c2 = 2.f * alpha * 10.f * LOG2E;

  const float* x = q_fp + (size_t)row * FEAT;
  float xs[FEAT];
  #pragma unroll
  for (int f = 0; f < FEAT; ++f) xs[f] = x[f];

  float s = bq_s[t];
  #pragma unroll
  for (int f = 0; f < SP_; ++f) s += xs[f] * Wq_s[t * SP_ + f];
  float w = bq_w[t];
  #pragma unroll
  for (int f = 0; f < WD_; ++f) w += xs[SP_ + f] * Wq_w[t * WD_ + f];

  const int h = t >> 5, d = t & 31;
  const int b = row >> 10, q = row & (LQ - 1);
  const size_t base = ((size_t)(b * H_ + h) * LQ + q) * 64;
  Qh[base + d]      = f2bf(c1 * s);
  Qh[base + 32 + d] = f2bf(c2 * w);
}

// ---------------------------------------------------------------------------
// Fused K/V projection + fragment prepack. Block = (64-k tile, bh).
// Thread (k_local = t>>2, part = t&3) computes 8 struct + 8 wave + 8 value
// features for head h, writes K granules directly, V via LDS transpose.
// KV granule map (16B granules, 768 per tile):
//   K: (t4*2+half)*64 + quad*16 + lo  holds feat[quad*8+half*32 ..8] of
//      k = off(t4) + perm(lo),  off(t4)={0,4,32,36}, perm(lo)=(lo>>2)*8+(lo&3)
//   V: 512 + (dt*2+kw)*64 + quad*16+lo holds V^T[d=dt*16+lo][kw*32+quad*8 ..8]
// ---------------------------------------------------------------------------
__global__ __launch_bounds__(256) void projk_pack_kernel(
    const float* __restrict__ v_ret, const float* __restrict__ Wk_s,
    const float* __restrict__ bk_s, const float* __restrict__ Wk_w,
    const float* __restrict__ bk_w, const float* __restrict__ Wv,
    const float* __restrict__ bv,   const float* __restrict__ wb,
    short* __restrict__ KV, float* __restrict__ kb)
{
  __shared__ float ldsv[64][33];
  const int blk = blockIdx.x, bh = blockIdx.y;
  const int b = bh >> 3, h = bh & 7;
  const int t = threadIdx.x;
  const int kl = t >> 2, part = t & 3;
  const int k = blk * 64 + kl;
  const float alpha = sigmoidf_(wb[0]);

  const float* x = v_ret + (size_t)(b * LK + k) * FEAT;
  float xs[FEAT];
  #pragma unroll
  for (int f = 0; f < FEAT; ++f) xs[f] = x[f];

  float s8[8], w8[8], v8[8];
  #pragma unroll
  for (int i = 0; i < 8; ++i) {
    const int d = h * 32 + part * 8 + i;
    float s = bk_s[d];
    #pragma unroll
    for (int f = 0; f < SP_; ++f) s += xs[f] * Wk_s[d * SP_ + f];
    float w = bk_w[d];
    #pragma unroll
    for (int f = 0; f < WD_; ++f) w += xs[SP_ + f] * Wk_w[d * WD_ + f];
    float v = bv[d];
    #pragma unroll
    for (int f = 0; f < FEAT; ++f) v += xs[f] * Wv[d * FEAT + f];
    s8[i] = s; w8[i] = w; v8[i] = v;
    ldsv[kl][part * 8 + i] = v;
  }

  // kb = -(alpha/TEMP)*log2e*||w||^2  (reduce over 4 consecutive lanes)
  float sq = 0.f;
  #pragma unroll
  for (int i = 0; i < 8; ++i) sq += w8[i] * w8[i];
  sq += __shfl_xor(sq, 1);
  sq += __shfl_xor(sq, 2);
  if (part == 0) kb[(size_t)bh * LK + k] = -10.f * alpha * LOG2E * sq;

  // K granules: decompose k_local -> (t4, lo)
  const int a  = kl >> 5;
  const int bb = (kl >> 2) & 1;
  const int p  = kl - a * 32 - bb * 4;
  const int lo = ((p >> 3) << 2) | (p & 3);
  const int t4 = a * 2 + bb;
  const size_t base = ((size_t)bh * 32 + blk) * 768;

  bf16x8 hs, hw;
  #pragma unroll
  for (int i = 0; i < 8; ++i) { hs[i] = f2bf(s8[i]); hw[i] = f2bf(w8[i]); }
  *(bf16x8*)(KV + (base + (t4 * 2 + 0) * 64 + part * 16 + lo) * 8) = hs;
  *(bf16x8*)(KV + (base + (t4 * 2 + 1) * 64 + part * 16 + lo) * 8) = hw;

  __syncthreads();

  // V granules: thread t = granule index (0..255)
  {
    const int j = t >> 6, l = t & 63;
    const int dt = j >> 1, kw = j & 1;
    const int lo2 = l & 15, quad = l >> 4;
    const int d = dt * 16 + lo2;
    bf16x8 hv;
    #pragma unroll
    for (int i = 0; i < 8; ++i)
      hv[i] = f2bf(ldsv[kw * 32 + quad * 8 + i][d]);
    *(bf16x8*)(KV + (base + 512 + t) * 8) = hv;
  }
}

// ---------------------------------------------------------------------------
// pi prepack: reorder pi[b][q][k] into fragment-lane order so attn's pi
// loads are lane-linear. One granule (f32x4) per thread.
// piP tile = (b, qt=q>>4, kblk=k>>6): 256 granules; granule g = t4*64+lane,
// lane=(quad,lo): holds pi[b][qt*16+lo][kblk*64 + off(t4)+quad*8 .. +4]
// ---------------------------------------------------------------------------
__global__ __launch_bounds__(256) void pi_prepack_kernel(
    const float* __restrict__ pi, float* __restrict__ piP)
{
  const int Gid = blockIdx.x * 256 + threadIdx.x;
  const int g    = Gid & 255;
  const int kblk = (Gid >> 8) & 31;
  const int qt   = (Gid >> 13) & 63;
  const int b    = Gid >> 19;
  const int t4 = g >> 6, l = g & 63;
  const int lo = l & 15, quad = l >> 4;
  const int q = qt * 16 + lo;
  const int k = kblk * 64 + ((t4 >> 1) << 5) + ((t4 & 1) << 2) + quad * 8;
  const f32x4 v = *(const f32x4*)(pi + ((size_t)(b * LQ + q) * LK + k));
  *(f32x4*)(piP + (size_t)Gid * 4) = v;
}

// ---------------------------------------------------------------------------
// Flash attention: LDS-staged K/V (double buffer, global_load_lds), MFMA,
// log-free softmax p = pi * exp2(s + kb - m), coalesced piP loads.
// ---------------------------------------------------------------------------
union PF { int i[4]; bf16x8 v; };

__global__ __launch_bounds__(256, 4) void attn_kernel(
    const short* __restrict__ Qh, const short* __restrict__ KV,
    const float* __restrict__ kb, const float* __restrict__ piP,
    float* __restrict__ part)
{
  __shared__ short skv[2][6144];   // 2 x 768 granules x 16 B
  const int bh = blockIdx.y;
  const int sp = blockIdx.z;
  const int b = bh >> 3;
  const int wv = threadIdx.x >> 6;
  const int lane = threadIdx.x & 63;
  const int lo16 = lane & 15;
  const int quad = lane >> 4;
  const int q = blockIdx.x * 64 + wv * 16 + lo16;
  const int qt = blockIdx.x * 4 + wv;
  const int k0 = sp * KPS;
  const int blk0 = sp * 16;

  const size_t qoff = ((size_t)bh * LQ + q) * 64 + quad * 8;
  const bf16x8 qh0 = *(const bf16x8*)(Qh + qoff);
  const bf16x8 qh1 = *(const bf16x8*)(Qh + qoff + 32);

  const float* pibase = piP + (((size_t)(b * 64 + qt) * 32 + blk0) << 10) + lane * 4;
  const float* kbbase = kb + (size_t)bh * LK + k0 + quad * 8;

  float m = -1e30f, l = 0.f;
  f32x4 o0 = {0.f, 0.f, 0.f, 0.f}, o1 = {0.f, 0.f, 0.f, 0.f};

  // prologue stage into buffer 0
  {
    const size_t gb = ((size_t)bh * 32 + blk0) * 768;
    #pragma unroll
    for (int c = 0; c < 3; ++c)
      gl_lds16(KV + (gb + c * 256 + wv * 64 + lane) * 8,
               &skv[0][c * 2048 + wv * 512]);
  }

  #pragma unroll 2
  for (int it = 0; it < ITERS; ++it) {
    __syncthreads();   // drains previous stage; buffer (it&1) ready
    if (it + 1 < ITERS) {
      const size_t gb = ((size_t)bh * 32 + blk0 + it + 1) * 768;
      short* db = skv[(it + 1) & 1];
      #pragma unroll
      for (int c = 0; c < 3; ++c)
        gl_lds16(KV + (gb + c * 256 + wv * 64 + lane) * 8,
                 db + c * 2048 + wv * 512);
    }
    const short* cbuf = skv[it & 1];

    // pi (coalesced, fragment-ordered) / kb (broadcast) loads
    const float* pp = pibase + (it << 10);
    f32x4 pi4[4];
    #pragma unroll
    for (int t4 = 0; t4 < 4; ++t4) pi4[t4] = *(const f32x4*)(pp + t4 * 256);
    const float* bp = kbbase + it * 64;
    f32x4 kb4[4];
    kb4[0] = *(const f32x4*)(bp);      kb4[1] = *(const f32x4*)(bp + 4);
    kb4[2] = *(const f32x4*)(bp + 32); kb4[3] = *(const f32x4*)(bp + 36);

    // QK^T from LDS fragments (lane-linear, conflict-free)
    f32x4 st[4];
    #pragma unroll
    for (int t4 = 0; t4 < 4; ++t4) {
      const bf16x8 ka0 = *(const bf16x8*)(cbuf + ((t4 * 2 + 0) * 64 + lane) * 8);
      const bf16x8 ka1 = *(const bf16x8*)(cbuf + ((t4 * 2 + 1) * 64 + lane) * 8);
      f32x4 z = {0.f, 0.f, 0.f, 0.f};
      z = __builtin_amdgcn_mfma_f32_16x16x32_bf16(ka0, qh0, z, 0, 0, 0);
      z = __builtin_amdgcn_mfma_f32_16x16x32_bf16(ka1, qh1, z, 0, 0, 0);
      st[t4] = z;
    }

    // logits = s + kb (log2-domain); pi multiplied after exp2
    float lg[16];
    #pragma unroll
    for (int t4 = 0; t4 < 4; ++t4) {
      #pragma unroll
      for (int r = 0; r < 4; ++r) lg[t4 * 4 + r] = st[t4][r] + kb4[t4][r];
    }

    float cm = lg[0];
    #pragma unroll
    for (int j = 1; j < 16; ++j) cm = fmaxf(cm, lg[j]);
    cm = fmaxf(cm, __shfl_xor(cm, 16));
    cm = fmaxf(cm, __shfl_xor(cm, 32));
    const float mn = fmaxf(m, cm);
    const float sc = __builtin_amdgcn_exp2f(m - mn);

    unsigned eu[16];
    #pragma unroll
    for (int t4 = 0; t4 < 4; ++t4) {
      #pragma unroll
      for (int r = 0; r < 4; ++r)
        eu[t4 * 4 + r] = __float_as_uint(
            __builtin_amdgcn_exp2f(lg[t4 * 4 + r] - mn) * fmaxf(pi4[t4][r], 1e-9f));
    }

    PF pf0, pf1;
    float ps = 0.f;
    #pragma unroll
    for (int p = 0; p < 4; ++p) {
      const int w0 = __builtin_amdgcn_perm(eu[2 * p + 1], eu[2 * p], 0x07060302u);
      const int w1 = __builtin_amdgcn_perm(eu[8 + 2 * p + 1], eu[8 + 2 * p], 0x07060302u);
      pf0.i[p] = w0; pf1.i[p] = w1;
      ps += __uint_as_float(((unsigned)w0) << 16) + __uint_as_float(w0 & 0xffff0000u);
      ps += __uint_as_float(((unsigned)w1) << 16) + __uint_as_float(w1 & 0xffff0000u);
    }
    ps += __shfl_xor(ps, 16);
    ps += __shfl_xor(ps, 32);
    l = l * sc + ps;
    m = mn;
    #pragma unroll
    for (int r = 0; r < 4; ++r) { o0[r] *= sc; o1[r] *= sc; }

    // PV from LDS V fragments
    const bf16x8 va00 = *(const bf16x8*)(cbuf + ((512 + 0 * 64) + lane) * 8);
    const bf16x8 va01 = *(const bf16x8*)(cbuf + ((512 + 1 * 64) + lane) * 8);
    const bf16x8 va10 = *(const bf16x8*)(cbuf + ((512 + 2 * 64) + lane) * 8);
    const bf16x8 va11 = *(const bf16x8*)(cbuf + ((512 + 3 * 64) + lane) * 8);
    o0 = __builtin_amdgcn_mfma_f32_16x16x32_bf16(va00, pf0.v, o0, 0, 0, 0);
    o0 = __builtin_amdgcn_mfma_f32_16x16x32_bf16(va01, pf1.v, o0, 0, 0, 0);
    o1 = __builtin_amdgcn_mfma_f32_16x16x32_bf16(va10, pf0.v, o1, 0, 0, 0);
    o1 = __builtin_amdgcn_mfma_f32_16x16x32_bf16(va11, pf1.v, o1, 0, 0, 0);
  }

  // partial out: [sp][bh][q] stride 36 floats: m, l, _, _, o[32]
  float* ppart = part + ((size_t)(sp * 32 + bh) * LQ + q) * 36;
  if (quad == 0) { ppart[0] = m; ppart[1] = l; }
  *(f32x4*)(ppart + 4 + quad * 4)  = o0;
  *(f32x4*)(ppart + 20 + quad * 4) = o1;
}

// ---------------------------------------------------------------------------
// Fused combine + out GEMM: stage ctx rows by merging SPLIT partials, then
// out = ctx @ Wo^T + bo.  256 blocks of 16 rows; thread: 4 rows x 4 cols.
// ---------------------------------------------------------------------------
__global__ __launch_bounds__(256) void out_kernel(
    const float* __restrict__ part, const float* __restrict__ Wo,
    const float* __restrict__ bo, float* __restrict__ out)
{
  __shared__ float cs[16 * 256];
  const int t = threadIdx.x;
  const size_t r0 = (size_t)blockIdx.x * 16;   // global ctx row = b*LQ + q

  // staging: thread covers f32x4 at (row = i*4 + t>>6, col4 = (t&63)*4)
  {
    const int col4 = (t & 63) * 4;
    const int h = col4 >> 5, d = col4 & 31;
    #pragma unroll
    for (int i = 0; i < 4; ++i) {
      const int row = i * 4 + (t >> 6);
      const size_t gq = r0 + row;
      const int b = (int)(gq >> 10), qq = (int)(gq & (LQ - 1));
      const size_t r = ((size_t)(b * H_ + h) * LQ + qq);
      const float* p0 = part + r * 36;
      const float* p1 = part + (r + (size_t)B_ * H_ * LQ) * 36;
      const float m0 = p0[0], l0 = p0[1], m1 = p1[0], l1 = p1[1];
      const float mM = fmaxf(m0, m1);
      const float w0 = __builtin_amdgcn_exp2f(m0 - mM);
      const float w1 = __builtin_amdgcn_exp2f(m1 - mM);
      const float inv = 1.f / (w0 * l0 + w1 * l1);
      const f32x4 a0 = *(const f32x4*)(p0 + 4 + d);
      const f32x4 a1 = *(const f32x4*)(p1 + 4 + d);
      f32x4 cv;
      #pragma unroll
      for (int j = 0; j < 4; ++j) cv[j] = (w0 * a0[j] + w1 * a1[j]) * inv;
      *(f32x4*)(cs + row * 256 + col4) = cv;
    }
  }
  __syncthreads();

  const int o0 = (t & 63) * 4;
  const int rs = (t >> 6) * 4;
  float acc[4][4];
  #pragma unroll
  for (int r = 0; r < 4; ++r) {
    #pragma unroll
    for (int j = 0; j < 4; ++j) acc[r][j] = bo[o0 + j];
  }

  for (int c4 = 0; c4 < 64; ++c4) {
    const f32x4 w0 = *(const f32x4*)(Wo + (size_t)(o0 + 0) * HID_ + c4 * 4);
    const f32x4 w1 = *(const f32x4*)(Wo + (size_t)(o0 + 1) * HID_ + c4 * 4);
    const f32x4 w2 = *(const f32x4*)(Wo + (size_t)(o0 + 2) * HID_ + c4 * 4);
    const f32x4 w3 = *(const f32x4*)(Wo + (size_t)(o0 + 3) * HID_ + c4 * 4);
    #pragma unroll
    for (int r = 0; r < 4; ++r) {
      const f32x4 cv = *(const f32x4*)(cs + (rs + r) * 256 + c4 * 4);
      acc[r][0] += cv[0] * w0[0] + cv[1] * w0[1] + cv[2] * w0[2] + cv[3] * w0[3];
      acc[r][1] += cv[0] * w1[0] + cv[1] * w1[1] + cv[2] * w1[2] + cv[3] * w1[3];
      acc[r][2] += cv[0] * w2[0] + cv[1] * w2[1] + cv[2] * w2[2] + cv[3] * w2[3];
      acc[r][3] += cv[0] * w3[0] + cv[1] * w3[1] + cv[2] * w3[2] + cv[3] * w3[3];
    }
  }
  #pragma unroll
  for (int r = 0; r < 4; ++r) {
    f32x4 res;
    res[0] = acc[r][0]; res[1] = acc[r][1]; res[2] = acc[r][2]; res[3] = acc[r][3];
    *(f32x4*)(out + (r0 + rs + r) * HID_ + o0) = res;
  }
}

// ---------------------------------------------------------------------------
extern "C" void kernel_launch(void* const* d_in, const int* in_sizes, int n_in,
                              void* d_out, int out_size, void* d_ws, size_t ws_size,
                              hipStream_t stream)
{
  const float* q_fp  = (const float*)d_in[0];
  const float* v_ret = (const float*)d_in[1];
  const float* pi    = (const float*)d_in[2];
  const float* Wq_s  = (const float*)d_in[3];
  const float* bq_s  = (const float*)d_in[4];
  const float* Wk_s  = (const float*)d_in[5];
  const float* bk_s  = (const float*)d_in[6];
  const float* Wq_w  = (const float*)d_in[7];
  const float* bq_w  = (const float*)d_in[8];
  const float* Wk_w  = (const float*)d_in[9];
  const float* bk_w  = (const float*)d_in[10];
  const float* Wv    = (const float*)d_in[11];
  const float* bv    = (const float*)d_in[12];
  const float* Wo    = (const float*)d_in[13];
  const float* bo    = (const float*)d_in[14];
  const float* wb    = (const float*)d_in[15];
  float* out = (float*)d_out;

  // ws: Qh 4MB | KV 12MB | kb 256KB | piP 32MB | part 9MB  (~57.3 MB)
  short* Qh   = (short*)d_ws;                     // 2,097,152 sh
  short* KV   = Qh + (size_t)2097152;             // 6,291,456 sh
  float* kbuf = (float*)(KV + (size_t)6291456);   //    65,536 fl
  float* piP  = kbuf + (size_t)65536;             // 8,388,608 fl
  float* part = piP + (size_t)8388608;            // 2,359,296 fl

  proj_q_kernel<<<B_ * LQ, 256, 0, stream>>>(q_fp, Wq_s, bq_s, Wq_w, bq_w, wb, Qh);
  projk_pack_kernel<<<dim3(LK / 64, 32), 256, 0, stream>>>(
      v_ret, Wk_s, bk_s, Wk_w, bk_w, Wv, bv, wb, KV, kbuf);
  pi_prepack_kernel<<<8192, 256, 0, stream>>>(pi, piP);
  attn_kernel<<<dim3(LQ / 64, 32, SPLIT), 256, 0, stream>>>(Qh, KV, kbuf, piP, part);
  out_kernel<<<(B_ * LQ) / 16, 256, 0, stream>>>(part, Wo, bo, out);
}

// Round 6
// 179.059 us; speedup vs baseline: 1.6073x; 1.1463x over previous
//
#include <hip/hip_runtime.h>
#include <hip/hip_bf16.h>
#include <cstdint>

#define B_    4
#define LQ    1024
#define LK    2048
#define FEAT  11
#define SP_   8
#define WD_   3
#define H_    8
#define HID_  256
#define LOG2E 1.4426950408889634f
#define SPLIT 2
#define KPS   (LK / SPLIT)    // 1024 k per split
#define ITERS (KPS / 64)      // 16 iterations of 64 k

typedef __attribute__((ext_vector_type(4))) float f32x4;
typedef __attribute__((ext_vector_type(8))) short bf16x8;
typedef __attribute__((ext_vector_type(4))) short s16x4;

__device__ __forceinline__ float sigmoidf_(float x) { return 1.f / (1.f + __expf(-x)); }

__device__ __forceinline__ short f2bf(float f) {
  unsigned u = __float_as_uint(f);
  u += 0x7fffu + ((u >> 16) & 1u);
  return (short)(u >> 16);
}
__device__ __forceinline__ float bf2f(short s) {
  return __uint_as_float(((unsigned)(unsigned short)s) << 16);
}

__device__ __forceinline__ void gl_lds16(const void* g, void* l) {
  __builtin_amdgcn_global_load_lds(
      (const __attribute__((address_space(1))) unsigned int*)g,
      (__attribute__((address_space(3))) unsigned int*)l, 16, 0, 0);
}

// ---------------------------------------------------------------------------
// Q projection -> Qh bf16 [bh][q][64]; scales (c1,c2) and log2e folded in.
// ---------------------------------------------------------------------------
__global__ __launch_bounds__(256) void proj_q_kernel(
    const float* __restrict__ q_fp, const float* __restrict__ Wq_s,
    const float* __restrict__ bq_s, const float* __restrict__ Wq_w,
    const float* __restrict__ bq_w, const float* __restrict__ wb,
    short* __restrict__ Qh)
{
  const int row = blockIdx.x;            // b*LQ + q
  const int t   = threadIdx.x;           // h*32 + d
  const float alpha = sigmoidf_(wb[0]);
  const float c1 = (1.f - alpha) * 0.17677669529663687f * LOG2E;
  const float c2 = 2.f * alpha * 10.f * LOG2E;

  const float* x = q_fp + (size_t)row * FEAT;
  float xs[FEAT];
  #pragma unroll
  for (int f = 0; f < FEAT; ++f) xs[f] = x[f];

  float s = bq_s[t];
  #pragma unroll
  for (int f = 0; f < SP_; ++f) s += xs[f] * Wq_s[t * SP_ + f];
  float w = bq_w[t];
  #pragma unroll
  for (int f = 0; f < WD_; ++f) w += xs[SP_ + f] * Wq_w[t * WD_ + f];

  const int h = t >> 5, d = t & 31;
  const int b = row >> 10, q = row & (LQ - 1);
  const size_t base = ((size_t)(b * H_ + h) * LQ + q) * 64;
  Qh[base + d]      = f2bf(c1 * s);
  Qh[base + 32 + d] = f2bf(c2 * w);
}

// ---------------------------------------------------------------------------
// Fused K/V projection + fragment prepack. Block = (64-k tile, bh).
// ---------------------------------------------------------------------------
__global__ __launch_bounds__(256) void projk_pack_kernel(
    const float* __restrict__ v_ret, const float* __restrict__ Wk_s,
    const float* __restrict__ bk_s, const float* __restrict__ Wk_w,
    const float* __restrict__ bk_w, const float* __restrict__ Wv,
    const float* __restrict__ bv,   const float* __restrict__ wb,
    short* __restrict__ KV, float* __restrict__ kb)
{
  __shared__ float ldsv[64][33];
  const int blk = blockIdx.x, bh = blockIdx.y;
  const int b = bh >> 3, h = bh & 7;
  const int t = threadIdx.x;
  const int kl = t >> 2, part = t & 3;
  const int k = blk * 64 + kl;
  const float alpha = sigmoidf_(wb[0]);

  const float* x = v_ret + (size_t)(b * LK + k) * FEAT;
  float xs[FEAT];
  #pragma unroll
  for (int f = 0; f < FEAT; ++f) xs[f] = x[f];

  float s8[8], w8[8], v8[8];
  #pragma unroll
  for (int i = 0; i < 8; ++i) {
    const int d = h * 32 + part * 8 + i;
    float s = bk_s[d];
    #pragma unroll
    for (int f = 0; f < SP_; ++f) s += xs[f] * Wk_s[d * SP_ + f];
    float w = bk_w[d];
    #pragma unroll
    for (int f = 0; f < WD_; ++f) w += xs[SP_ + f] * Wk_w[d * WD_ + f];
    float v = bv[d];
    #pragma unroll
    for (int f = 0; f < FEAT; ++f) v += xs[f] * Wv[d * FEAT + f];
    s8[i] = s; w8[i] = w; v8[i] = v;
    ldsv[kl][part * 8 + i] = v;
  }

  float sq = 0.f;
  #pragma unroll
  for (int i = 0; i < 8; ++i) sq += w8[i] * w8[i];
  sq += __shfl_xor(sq, 1);
  sq += __shfl_xor(sq, 2);
  if (part == 0) kb[(size_t)bh * LK + k] = -10.f * alpha * LOG2E * sq;

  const int a  = kl >> 5;
  const int bb = (kl >> 2) & 1;
  const int p  = kl - a * 32 - bb * 4;
  const int lo = ((p >> 3) << 2) | (p & 3);
  const int t4 = a * 2 + bb;
  const size_t base = ((size_t)bh * 32 + blk) * 768;

  bf16x8 hs, hw;
  #pragma unroll
  for (int i = 0; i < 8; ++i) { hs[i] = f2bf(s8[i]); hw[i] = f2bf(w8[i]); }
  *(bf16x8*)(KV + (base + (t4 * 2 + 0) * 64 + part * 16 + lo) * 8) = hs;
  *(bf16x8*)(KV + (base + (t4 * 2 + 1) * 64 + part * 16 + lo) * 8) = hw;

  __syncthreads();

  {
    const int j = t >> 6, l = t & 63;
    const int dt = j >> 1, kw = j & 1;
    const int lo2 = l & 15, quad = l >> 4;
    const int d = dt * 16 + lo2;
    bf16x8 hv;
    #pragma unroll
    for (int i = 0; i < 8; ++i)
      hv[i] = f2bf(ldsv[kw * 32 + quad * 8 + i][d]);
    *(bf16x8*)(KV + (base + 512 + t) * 8) = hv;
  }
}

// ---------------------------------------------------------------------------
// pi prepack: reorder pi[b][q][k] into fragment-lane order.
// ---------------------------------------------------------------------------
__global__ __launch_bounds__(256) void pi_prepack_kernel(
    const float* __restrict__ pi, float* __restrict__ piP)
{
  const int Gid = blockIdx.x * 256 + threadIdx.x;
  const int g    = Gid & 255;
  const int kblk = (Gid >> 8) & 31;
  const int qt   = (Gid >> 13) & 63;
  const int b    = Gid >> 19;
  const int t4 = g >> 6, l = g & 63;
  const int lo = l & 15, quad = l >> 4;
  const int q = qt * 16 + lo;
  const int k = kblk * 64 + ((t4 >> 1) << 5) + ((t4 & 1) << 2) + quad * 8;
  const f32x4 v = *(const f32x4*)(pi + ((size_t)(b * LQ + q) * LK + k));
  *(f32x4*)(piP + (size_t)Gid * 4) = v;
}

// ---------------------------------------------------------------------------
// Flash attention: LDS-staged K/V (double buffer, global_load_lds), MFMA,
// log-free softmax p = pi * exp2(s + kb - m), coalesced piP loads.
// ---------------------------------------------------------------------------
union PF { int i[4]; bf16x8 v; };

__global__ __launch_bounds__(256, 4) void attn_kernel(
    const short* __restrict__ Qh, const short* __restrict__ KV,
    const float* __restrict__ kb, const float* __restrict__ piP,
    float* __restrict__ part)
{
  __shared__ short skv[2][6144];   // 2 x 768 granules x 16 B
  const int bh = blockIdx.y;
  const int sp = blockIdx.z;
  const int b = bh >> 3;
  const int wv = threadIdx.x >> 6;
  const int lane = threadIdx.x & 63;
  const int lo16 = lane & 15;
  const int quad = lane >> 4;
  const int q = blockIdx.x * 64 + wv * 16 + lo16;
  const int qt = blockIdx.x * 4 + wv;
  const int k0 = sp * KPS;
  const int blk0 = sp * 16;

  const size_t qoff = ((size_t)bh * LQ + q) * 64 + quad * 8;
  const bf16x8 qh0 = *(const bf16x8*)(Qh + qoff);
  const bf16x8 qh1 = *(const bf16x8*)(Qh + qoff + 32);

  const float* pibase = piP + (((size_t)(b * 64 + qt) * 32 + blk0) << 10) + lane * 4;
  const float* kbbase = kb + (size_t)bh * LK + k0 + quad * 8;

  float m = -1e30f, l = 0.f;
  f32x4 o0 = {0.f, 0.f, 0.f, 0.f}, o1 = {0.f, 0.f, 0.f, 0.f};

  {
    const size_t gb = ((size_t)bh * 32 + blk0) * 768;
    #pragma unroll
    for (int c = 0; c < 3; ++c)
      gl_lds16(KV + (gb + c * 256 + wv * 64 + lane) * 8,
               &skv[0][c * 2048 + wv * 512]);
  }

  #pragma unroll 2
  for (int it = 0; it < ITERS; ++it) {
    __syncthreads();   // drains previous stage; buffer (it&1) ready
    if (it + 1 < ITERS) {
      const size_t gb = ((size_t)bh * 32 + blk0 + it + 1) * 768;
      short* db = skv[(it + 1) & 1];
      #pragma unroll
      for (int c = 0; c < 3; ++c)
        gl_lds16(KV + (gb + c * 256 + wv * 64 + lane) * 8,
                 db + c * 2048 + wv * 512);
    }
    const short* cbuf = skv[it & 1];

    const float* pp = pibase + (it << 10);
    f32x4 pi4[4];
    #pragma unroll
    for (int t4 = 0; t4 < 4; ++t4) pi4[t4] = *(const f32x4*)(pp + t4 * 256);
    const float* bp = kbbase + it * 64;
    f32x4 kb4[4];
    kb4[0] = *(const f32x4*)(bp);      kb4[1] = *(const f32x4*)(bp + 4);
    kb4[2] = *(const f32x4*)(bp + 32); kb4[3] = *(const f32x4*)(bp + 36);

    f32x4 st[4];
    #pragma unroll
    for (int t4 = 0; t4 < 4; ++t4) {
      const bf16x8 ka0 = *(const bf16x8*)(cbuf + ((t4 * 2 + 0) * 64 + lane) * 8);
      const bf16x8 ka1 = *(const bf16x8*)(cbuf + ((t4 * 2 + 1) * 64 + lane) * 8);
      f32x4 z = {0.f, 0.f, 0.f, 0.f};
      z = __builtin_amdgcn_mfma_f32_16x16x32_bf16(ka0, qh0, z, 0, 0, 0);
      z = __builtin_amdgcn_mfma_f32_16x16x32_bf16(ka1, qh1, z, 0, 0, 0);
      st[t4] = z;
    }

    float lg[16];
    #pragma unroll
    for (int t4 = 0; t4 < 4; ++t4) {
      #pragma unroll
      for (int r = 0; r < 4; ++r) lg[t4 * 4 + r] = st[t4][r] + kb4[t4][r];
    }

    float cm = lg[0];
    #pragma unroll
    for (int j = 1; j < 16; ++j) cm = fmaxf(cm, lg[j]);
    cm = fmaxf(cm, __shfl_xor(cm, 16));
    cm = fmaxf(cm, __shfl_xor(cm, 32));
    const float mn = fmaxf(m, cm);
    const float sc = __builtin_amdgcn_exp2f(m - mn);

    unsigned eu[16];
    #pragma unroll
    for (int t4 = 0; t4 < 4; ++t4) {
      #pragma unroll
      for (int r = 0; r < 4; ++r)
        eu[t4 * 4 + r] = __float_as_uint(
            __builtin_amdgcn_exp2f(lg[t4 * 4 + r] - mn) * fmaxf(pi4[t4][r], 1e-9f));
    }

    PF pf0, pf1;
    float ps = 0.f;
    #pragma unroll
    for (int p = 0; p < 4; ++p) {
      const int w0 = __builtin_amdgcn_perm(eu[2 * p + 1], eu[2 * p], 0x07060302u);
      const int w1 = __builtin_amdgcn_perm(eu[8 + 2 * p + 1], eu[8 + 2 * p], 0x07060302u);
      pf0.i[p] = w0; pf1.i[p] = w1;
      ps += __uint_as_float(((unsigned)w0) << 16) + __uint_as_float(w0 & 0xffff0000u);
      ps += __uint_as_float(((unsigned)w1) << 16) + __uint_as_float(w1 & 0xffff0000u);
    }
    ps += __shfl_xor(ps, 16);
    ps += __shfl_xor(ps, 32);
    l = l * sc + ps;
    m = mn;
    #pragma unroll
    for (int r = 0; r < 4; ++r) { o0[r] *= sc; o1[r] *= sc; }

    const bf16x8 va00 = *(const bf16x8*)(cbuf + ((512 + 0 * 64) + lane) * 8);
    const bf16x8 va01 = *(const bf16x8*)(cbuf + ((512 + 1 * 64) + lane) * 8);
    const bf16x8 va10 = *(const bf16x8*)(cbuf + ((512 + 2 * 64) + lane) * 8);
    const bf16x8 va11 = *(const bf16x8*)(cbuf + ((512 + 3 * 64) + lane) * 8);
    o0 = __builtin_amdgcn_mfma_f32_16x16x32_bf16(va00, pf0.v, o0, 0, 0, 0);
    o0 = __builtin_amdgcn_mfma_f32_16x16x32_bf16(va01, pf1.v, o0, 0, 0, 0);
    o1 = __builtin_amdgcn_mfma_f32_16x16x32_bf16(va10, pf0.v, o1, 0, 0, 0);
    o1 = __builtin_amdgcn_mfma_f32_16x16x32_bf16(va11, pf1.v, o1, 0, 0, 0);
  }

  // partial out: [sp][bh][q] stride 36 floats: m, l, _, _, o[32]
  float* ppart = part + ((size_t)(sp * 32 + bh) * LQ + q) * 36;
  if (quad == 0) { ppart[0] = m; ppart[1] = l; }
  *(f32x4*)(ppart + 4 + quad * 4)  = o0;
  *(f32x4*)(ppart + 20 + quad * 4) = o1;
}

// ---------------------------------------------------------------------------
// Wo -> bf16 hi/lo split (row-major [n][k], same as Wo).
// ---------------------------------------------------------------------------
__global__ __launch_bounds__(256) void wo_prep_kernel(
    const float* __restrict__ Wo, short* __restrict__ WoH, short* __restrict__ WoL)
{
  const int i = (blockIdx.x * 256 + threadIdx.x) * 4;
  const f32x4 v = *(const f32x4*)(Wo + i);
  s16x4 h, l;
  #pragma unroll
  for (int j = 0; j < 4; ++j) {
    h[j] = f2bf(v[j]);
    l[j] = f2bf(v[j] - bf2f(h[j]));
  }
  *(s16x4*)(WoH + i) = h;
  *(s16x4*)(WoL + i) = l;
}

// ---------------------------------------------------------------------------
// Fused combine + output GEMM via MFMA (hi/lo bf16 compensation).
// Block = 16 ctx rows (m-tile); wave w covers out cols [w*64, w*64+64).
// A-frag: lane(lo16=m, quad): window win (=head h): part o[d=quad*8..+8],
// split-merged, hi/lo bf16. B-frag: WoH/WoL rows (n=lo16), k=win*32+quad*8.
// C: col=lo16 (n), row=quad*4+r (m). out = Ah*Bh + Al*Bh + Ah*Bl + bias.
// ---------------------------------------------------------------------------
__global__ __launch_bounds__(256) void out_kernel(
    const float* __restrict__ part, const short* __restrict__ WoH,
    const short* __restrict__ WoL, const float* __restrict__ bo,
    float* __restrict__ out)
{
  const int t = threadIdx.x;
  const int wv = t >> 6, lane = t & 63;
  const int lo16 = lane & 15, quad = lane >> 4;
  const int mt = blockIdx.x;                 // m-tile of 16 rows
  const size_t gq = (size_t)mt * 16 + lo16;  // ctx row for A fragment
  const int b = (int)(gq >> 10), qq = (int)(gq & (LQ - 1));

  // ---- A fragments (8 windows = 8 heads), combine SPLIT partials ----
  bf16x8 Ah[8], Al[8];
  #pragma unroll
  for (int win = 0; win < 8; ++win) {
    const size_t r = (size_t)(b * H_ + win) * LQ + qq;
    const float* p0 = part + r * 36;
    const float* p1 = part + (r + (size_t)B_ * H_ * LQ) * 36;
    const float m0 = p0[0], l0 = p0[1], m1 = p1[0], l1 = p1[1];
    const float mM = fmaxf(m0, m1);
    const float w0 = __builtin_amdgcn_exp2f(m0 - mM);
    const float w1 = __builtin_amdgcn_exp2f(m1 - mM);
    const float inv = 1.f / (w0 * l0 + w1 * l1);
    const f32x4 a0  = *(const f32x4*)(p0 + 4 + quad * 8);
    const f32x4 a0b = *(const f32x4*)(p0 + 8 + quad * 8);
    const f32x4 a1  = *(const f32x4*)(p1 + 4 + quad * 8);
    const f32x4 a1b = *(const f32x4*)(p1 + 8 + quad * 8);
    float c8[8];
    #pragma unroll
    for (int j = 0; j < 4; ++j) {
      c8[j]     = (w0 * a0[j]  + w1 * a1[j])  * inv;
      c8[4 + j] = (w0 * a0b[j] + w1 * a1b[j]) * inv;
    }
    #pragma unroll
    for (int j = 0; j < 8; ++j) {
      const short hi = f2bf(c8[j]);
      Ah[win][j] = hi;
      Al[win][j] = f2bf(c8[j] - bf2f(hi));
    }
  }

  // ---- 4 n-tiles of 16 cols each ----
  const int n0 = wv * 64;
  #pragma unroll
  for (int nt = 0; nt < 4; ++nt) {
    const int nb = n0 + nt * 16;
    const short* bh = WoH + (size_t)(nb + lo16) * HID_ + quad * 8;
    const short* bl = WoL + (size_t)(nb + lo16) * HID_ + quad * 8;
    const float bias = bo[nb + lo16];
    f32x4 acc = {bias, bias, bias, bias};
    #pragma unroll
    for (int win = 0; win < 8; ++win) {
      const bf16x8 Bh = *(const bf16x8*)(bh + win * 32);
      const bf16x8 Bl = *(const bf16x8*)(bl + win * 32);
      acc = __builtin_amdgcn_mfma_f32_16x16x32_bf16(Ah[win], Bh, acc, 0, 0, 0);
      acc = __builtin_amdgcn_mfma_f32_16x16x32_bf16(Al[win], Bh, acc, 0, 0, 0);
      acc = __builtin_amdgcn_mfma_f32_16x16x32_bf16(Ah[win], Bl, acc, 0, 0, 0);
    }
    #pragma unroll
    for (int r4 = 0; r4 < 4; ++r4)
      out[(size_t)(mt * 16 + quad * 4 + r4) * HID_ + nb + lo16] = acc[r4];
  }
}

// ---------------------------------------------------------------------------
extern "C" void kernel_launch(void* const* d_in, const int* in_sizes, int n_in,
                              void* d_out, int out_size, void* d_ws, size_t ws_size,
                              hipStream_t stream)
{
  const float* q_fp  = (const float*)d_in[0];
  const float* v_ret = (const float*)d_in[1];
  const float* pi    = (const float*)d_in[2];
  const float* Wq_s  = (const float*)d_in[3];
  const float* bq_s  = (const float*)d_in[4];
  const float* Wk_s  = (const float*)d_in[5];
  const float* bk_s  = (const float*)d_in[6];
  const float* Wq_w  = (const float*)d_in[7];
  const float* bq_w  = (const float*)d_in[8];
  const float* Wk_w  = (const float*)d_in[9];
  const float* bk_w  = (const float*)d_in[10];
  const float* Wv    = (const float*)d_in[11];
  const float* bv    = (const float*)d_in[12];
  const float* Wo    = (const float*)d_in[13];
  const float* bo    = (const float*)d_in[14];
  const float* wb    = (const float*)d_in[15];
  float* out = (float*)d_out;

  // ws: Qh 4MB | KV 12MB | kb 256KB | piP 32MB | part 9MB  (~57.3 MB)
  short* Qh   = (short*)d_ws;                     // 2,097,152 sh
  short* KV   = Qh + (size_t)2097152;             // 6,291,456 sh
  float* kbuf = (float*)(KV + (size_t)6291456);   //    65,536 fl
  float* piP  = kbuf + (size_t)65536;             // 8,388,608 fl
  float* part = piP + (size_t)8388608;            // 2,359,296 fl
  // WoH/WoL alias the piP region (dead after attn_kernel completes)
  short* WoH  = (short*)piP;                      //    65,536 sh
  short* WoL  = WoH + (size_t)65536;              //    65,536 sh

  proj_q_kernel<<<B_ * LQ, 256, 0, stream>>>(q_fp, Wq_s, bq_s, Wq_w, bq_w, wb, Qh);
  projk_pack_kernel<<<dim3(LK / 64, 32), 256, 0, stream>>>(
      v_ret, Wk_s, bk_s, Wk_w, bk_w, Wv, bv, wb, KV, kbuf);
  pi_prepack_kernel<<<8192, 256, 0, stream>>>(pi, piP);
  attn_kernel<<<dim3(LQ / 64, 32, SPLIT), 256, 0, stream>>>(Qh, KV, kbuf, piP, part);
  wo_prep_kernel<<<64, 256, 0, stream>>>(Wo, WoH, WoL);
  out_kernel<<<(B_ * LQ) / 16, 256, 0, stream>>>(part, WoH, WoL, bo, out);
}

// Round 7
// 177.528 us; speedup vs baseline: 1.6211x; 1.0086x over previous
//
#include <hip/hip_runtime.h>
#include <hip/hip_bf16.h>
#include <cstdint>

#define B_    4
#define LQ    1024
#define LK    2048
#define FEAT  11
#define SP_   8
#define WD_   3
#define H_    8
#define HID_  256
#define LOG2E 1.4426950408889634f
#define SPLIT 2
#define KPS   (LK / SPLIT)    // 1024 k per split
#define ITERS (KPS / 64)      // 16 iterations of 64 k

typedef __attribute__((ext_vector_type(4))) float f32x4;
typedef __attribute__((ext_vector_type(8))) short bf16x8;
typedef __attribute__((ext_vector_type(4))) short s16x4;

__device__ __forceinline__ float sigmoidf_(float x) { return 1.f / (1.f + __expf(-x)); }

__device__ __forceinline__ short f2bf(float f) {
  unsigned u = __float_as_uint(f);
  u += 0x7fffu + ((u >> 16) & 1u);
  return (short)(u >> 16);
}
__device__ __forceinline__ float bf2f(short s) {
  return __uint_as_float(((unsigned)(unsigned short)s) << 16);
}

__device__ __forceinline__ void gl_lds16(const void* g, void* l) {
  __builtin_amdgcn_global_load_lds(
      (const __attribute__((address_space(1))) unsigned int*)g,
      (__attribute__((address_space(3))) unsigned int*)l, 16, 0, 0);
}

// ---------------------------------------------------------------------------
// Q projection -> Qh bf16 [bh][q][64]; scales (c1,c2) and log2e folded in.
// ---------------------------------------------------------------------------
__global__ __launch_bounds__(256) void proj_q_kernel(
    const float* __restrict__ q_fp, const float* __restrict__ Wq_s,
    const float* __restrict__ bq_s, const float* __restrict__ Wq_w,
    const float* __restrict__ bq_w, const float* __restrict__ wb,
    short* __restrict__ Qh)
{
  const int row = blockIdx.x;            // b*LQ + q
  const int t   = threadIdx.x;           // h*32 + d
  const float alpha = sigmoidf_(wb[0]);
  const float c1 = (1.f - alpha) * 0.17677669529663687f * LOG2E;
  const float c2 = 2.f * alpha * 10.f * LOG2E;

  const float* x = q_fp + (size_t)row * FEAT;
  float xs[FEAT];
  #pragma unroll
  for (int f = 0; f < FEAT; ++f) xs[f] = x[f];

  float s = bq_s[t];
  #pragma unroll
  for (int f = 0; f < SP_; ++f) s += xs[f] * Wq_s[t * SP_ + f];
  float w = bq_w[t];
  #pragma unroll
  for (int f = 0; f < WD_; ++f) w += xs[SP_ + f] * Wq_w[t * WD_ + f];

  const int h = t >> 5, d = t & 31;
  const int b = row >> 10, q = row & (LQ - 1);
  const size_t base = ((size_t)(b * H_ + h) * LQ + q) * 64;
  Qh[base + d]      = f2bf(c1 * s);
  Qh[base + 32 + d] = f2bf(c2 * w);
}

// ---------------------------------------------------------------------------
// Fused K/V projection + fragment prepack. Block = (64-k tile, bh).
// ---------------------------------------------------------------------------
__global__ __launch_bounds__(256) void projk_pack_kernel(
    const float* __restrict__ v_ret, const float* __restrict__ Wk_s,
    const float* __restrict__ bk_s, const float* __restrict__ Wk_w,
    const float* __restrict__ bk_w, const float* __restrict__ Wv,
    const float* __restrict__ bv,   const float* __restrict__ wb,
    short* __restrict__ KV, float* __restrict__ kb)
{
  __shared__ float ldsv[64][33];
  const int blk = blockIdx.x, bh = blockIdx.y;
  const int b = bh >> 3, h = bh & 7;
  const int t = threadIdx.x;
  const int kl = t >> 2, part = t & 3;
  const int k = blk * 64 + kl;
  const float alpha = sigmoidf_(wb[0]);

  const float* x = v_ret + (size_t)(b * LK + k) * FEAT;
  float xs[FEAT];
  #pragma unroll
  for (int f = 0; f < FEAT; ++f) xs[f] = x[f];

  float s8[8], w8[8], v8[8];
  #pragma unroll
  for (int i = 0; i < 8; ++i) {
    const int d = h * 32 + part * 8 + i;
    float s = bk_s[d];
    #pragma unroll
    for (int f = 0; f < SP_; ++f) s += xs[f] * Wk_s[d * SP_ + f];
    float w = bk_w[d];
    #pragma unroll
    for (int f = 0; f < WD_; ++f) w += xs[SP_ + f] * Wk_w[d * WD_ + f];
    float v = bv[d];
    #pragma unroll
    for (int f = 0; f < FEAT; ++f) v += xs[f] * Wv[d * FEAT + f];
    s8[i] = s; w8[i] = w; v8[i] = v;
    ldsv[kl][part * 8 + i] = v;
  }

  float sq = 0.f;
  #pragma unroll
  for (int i = 0; i < 8; ++i) sq += w8[i] * w8[i];
  sq += __shfl_xor(sq, 1);
  sq += __shfl_xor(sq, 2);
  if (part == 0) kb[(size_t)bh * LK + k] = -10.f * alpha * LOG2E * sq;

  const int a  = kl >> 5;
  const int bb = (kl >> 2) & 1;
  const int p  = kl - a * 32 - bb * 4;
  const int lo = ((p >> 3) << 2) | (p & 3);
  const int t4 = a * 2 + bb;
  const size_t base = ((size_t)bh * 32 + blk) * 768;

  bf16x8 hs, hw;
  #pragma unroll
  for (int i = 0; i < 8; ++i) { hs[i] = f2bf(s8[i]); hw[i] = f2bf(w8[i]); }
  *(bf16x8*)(KV + (base + (t4 * 2 + 0) * 64 + part * 16 + lo) * 8) = hs;
  *(bf16x8*)(KV + (base + (t4 * 2 + 1) * 64 + part * 16 + lo) * 8) = hw;

  __syncthreads();

  {
    const int j = t >> 6, l = t & 63;
    const int dt = j >> 1, kw = j & 1;
    const int lo2 = l & 15, quad = l >> 4;
    const int d = dt * 16 + lo2;
    bf16x8 hv;
    #pragma unroll
    for (int i = 0; i < 8; ++i)
      hv[i] = f2bf(ldsv[kw * 32 + quad * 8 + i][d]);
    *(bf16x8*)(KV + (base + 512 + t) * 8) = hv;
  }
}

// ---------------------------------------------------------------------------
// pi prepack: reorder pi[b][q][k] into fragment-lane order.
// ---------------------------------------------------------------------------
__global__ __launch_bounds__(256) void pi_prepack_kernel(
    const float* __restrict__ pi, float* __restrict__ piP)
{
  const int Gid = blockIdx.x * 256 + threadIdx.x;
  const int g    = Gid & 255;
  const int kblk = (Gid >> 8) & 31;
  const int qt   = (Gid >> 13) & 63;
  const int b    = Gid >> 19;
  const int t4 = g >> 6, l = g & 63;
  const int lo = l & 15, quad = l >> 4;
  const int q = qt * 16 + lo;
  const int k = kblk * 64 + ((t4 >> 1) << 5) + ((t4 & 1) << 2) + quad * 8;
  const f32x4 v = *(const f32x4*)(pi + ((size_t)(b * LQ + q) * LK + k));
  *(f32x4*)(piP + (size_t)Gid * 4) = v;
}

// ---------------------------------------------------------------------------
// Flash attention: LDS-staged K/V (double buffer, global_load_lds), MFMA,
// log-free softmax p = pi * exp2(s + kb - m), coalesced piP loads with
// distance-1 register prefetch; XCD-swizzled 1-D grid.
// ---------------------------------------------------------------------------
union PF { int i[4]; bf16x8 v; };

__device__ __forceinline__ void attn_step(
    const short* __restrict__ cbuf, bf16x8 qh0, bf16x8 qh1,
    const f32x4* __restrict__ pi4, const f32x4* __restrict__ kb4,
    int lane, float& m, float& l, f32x4& o0, f32x4& o1)
{
  // QK^T from LDS fragments (lane-linear, conflict-free)
  f32x4 st[4];
  #pragma unroll
  for (int t4 = 0; t4 < 4; ++t4) {
    const bf16x8 ka0 = *(const bf16x8*)(cbuf + ((t4 * 2 + 0) * 64 + lane) * 8);
    const bf16x8 ka1 = *(const bf16x8*)(cbuf + ((t4 * 2 + 1) * 64 + lane) * 8);
    f32x4 z = {0.f, 0.f, 0.f, 0.f};
    z = __builtin_amdgcn_mfma_f32_16x16x32_bf16(ka0, qh0, z, 0, 0, 0);
    z = __builtin_amdgcn_mfma_f32_16x16x32_bf16(ka1, qh1, z, 0, 0, 0);
    st[t4] = z;
  }

  float lg[16];
  #pragma unroll
  for (int t4 = 0; t4 < 4; ++t4) {
    #pragma unroll
    for (int r = 0; r < 4; ++r) lg[t4 * 4 + r] = st[t4][r] + kb4[t4][r];
  }

  float cm = lg[0];
  #pragma unroll
  for (int j = 1; j < 16; ++j) cm = fmaxf(cm, lg[j]);
  cm = fmaxf(cm, __shfl_xor(cm, 16));
  cm = fmaxf(cm, __shfl_xor(cm, 32));
  const float mn = fmaxf(m, cm);
  const float sc = __builtin_amdgcn_exp2f(m - mn);

  unsigned eu[16];
  #pragma unroll
  for (int t4 = 0; t4 < 4; ++t4) {
    #pragma unroll
    for (int r = 0; r < 4; ++r)
      eu[t4 * 4 + r] = __float_as_uint(
          __builtin_amdgcn_exp2f(lg[t4 * 4 + r] - mn) * pi4[t4][r]);
  }

  PF pf0, pf1;
  float ps = 0.f;
  #pragma unroll
  for (int p = 0; p < 4; ++p) {
    const int w0 = __builtin_amdgcn_perm(eu[2 * p + 1], eu[2 * p], 0x07060302u);
    const int w1 = __builtin_amdgcn_perm(eu[8 + 2 * p + 1], eu[8 + 2 * p], 0x07060302u);
    pf0.i[p] = w0; pf1.i[p] = w1;
    ps += __uint_as_float(((unsigned)w0) << 16) + __uint_as_float(w0 & 0xffff0000u);
    ps += __uint_as_float(((unsigned)w1) << 16) + __uint_as_float(w1 & 0xffff0000u);
  }
  ps += __shfl_xor(ps, 16);
  ps += __shfl_xor(ps, 32);
  l = l * sc + ps;
  m = mn;
  #pragma unroll
  for (int r = 0; r < 4; ++r) { o0[r] *= sc; o1[r] *= sc; }

  const bf16x8 va00 = *(const bf16x8*)(cbuf + ((512 + 0 * 64) + lane) * 8);
  const bf16x8 va01 = *(const bf16x8*)(cbuf + ((512 + 1 * 64) + lane) * 8);
  const bf16x8 va10 = *(const bf16x8*)(cbuf + ((512 + 2 * 64) + lane) * 8);
  const bf16x8 va11 = *(const bf16x8*)(cbuf + ((512 + 3 * 64) + lane) * 8);
  o0 = __builtin_amdgcn_mfma_f32_16x16x32_bf16(va00, pf0.v, o0, 0, 0, 0);
  o0 = __builtin_amdgcn_mfma_f32_16x16x32_bf16(va01, pf1.v, o0, 0, 0, 0);
  o1 = __builtin_amdgcn_mfma_f32_16x16x32_bf16(va10, pf0.v, o1, 0, 0, 0);
  o1 = __builtin_amdgcn_mfma_f32_16x16x32_bf16(va11, pf1.v, o1, 0, 0, 0);
}

__global__ __launch_bounds__(256, 4) void attn_kernel(
    const short* __restrict__ Qh, const short* __restrict__ KV,
    const float* __restrict__ kb, const float* __restrict__ piP,
    float* __restrict__ part)
{
  __shared__ short skv[2][6144];   // 2 x 768 granules x 16 B
  // XCD swizzle: blocks sharing (bh,sp) differ only in id>>6 -> same XCD
  const int id = blockIdx.x;
  const int combo = id & 63;       // (bh<<1) | sp
  const int qblk  = id >> 6;
  const int bh = combo >> 1;
  const int sp = combo & 1;
  const int b = bh >> 3;
  const int wv = threadIdx.x >> 6;
  const int lane = threadIdx.x & 63;
  const int lo16 = lane & 15;
  const int quad = lane >> 4;
  const int q  = qblk * 64 + wv * 16 + lo16;
  const int qt = qblk * 4 + wv;
  const int blk0 = sp * 16;

  const size_t qoff = ((size_t)bh * LQ + q) * 64 + quad * 8;
  const bf16x8 qh0 = *(const bf16x8*)(Qh + qoff);
  const bf16x8 qh1 = *(const bf16x8*)(Qh + qoff + 32);

  const float* pibase = piP + (((size_t)(b * 64 + qt) * 32 + blk0) << 10) + lane * 4;
  const float* kbbase = kb + (size_t)bh * LK + sp * KPS + quad * 8;

  float m = -1e30f, l = 0.f;
  f32x4 o0 = {0.f, 0.f, 0.f, 0.f}, o1 = {0.f, 0.f, 0.f, 0.f};

  // prologue: DMA buffer 0
  {
    const size_t gb = ((size_t)bh * 32 + blk0) * 768;
    #pragma unroll
    for (int c = 0; c < 3; ++c)
      gl_lds16(KV + (gb + c * 256 + wv * 64 + lane) * 8,
               &skv[0][c * 2048 + wv * 512]);
  }

  f32x4 piA[4], kbA[4], piB[4], kbB[4];
#define PI_LOAD(PID, KBD, IT) do {                                   \
    const float* pp_ = pibase + ((size_t)(IT) << 10);                \
    PID[0] = *(const f32x4*)(pp_);                                   \
    PID[1] = *(const f32x4*)(pp_ + 256);                             \
    PID[2] = *(const f32x4*)(pp_ + 512);                             \
    PID[3] = *(const f32x4*)(pp_ + 768);                             \
    const float* bp_ = kbbase + (IT) * 64;                           \
    KBD[0] = *(const f32x4*)(bp_);                                   \
    KBD[1] = *(const f32x4*)(bp_ + 4);                               \
    KBD[2] = *(const f32x4*)(bp_ + 32);                              \
    KBD[3] = *(const f32x4*)(bp_ + 36);                              \
  } while (0)

  PI_LOAD(piA, kbA, 0);

  for (int it = 0; it < ITERS; it += 2) {
    __syncthreads();   // DMA for buffer0 (it) complete; buffer1 free
    {
      const size_t gb = ((size_t)bh * 32 + blk0 + it + 1) * 768;
      #pragma unroll
      for (int c = 0; c < 3; ++c)
        gl_lds16(KV + (gb + c * 256 + wv * 64 + lane) * 8,
                 &skv[1][c * 2048 + wv * 512]);
    }
    PI_LOAD(piB, kbB, it + 1);                 // prefetch: used next half
    attn_step(skv[0], qh0, qh1, piA, kbA, lane, m, l, o0, o1);

    __syncthreads();   // DMA for buffer1 (it+1) complete; buffer0 free
    if (it + 2 < ITERS) {
      const size_t gb = ((size_t)bh * 32 + blk0 + it + 2) * 768;
      #pragma unroll
      for (int c = 0; c < 3; ++c)
        gl_lds16(KV + (gb + c * 256 + wv * 64 + lane) * 8,
                 &skv[0][c * 2048 + wv * 512]);
      PI_LOAD(piA, kbA, it + 2);               // prefetch: used next iter
    }
    attn_step(skv[1], qh0, qh1, piB, kbB, lane, m, l, o0, o1);
  }
#undef PI_LOAD

  // partial out: [sp][bh][q] stride 36 floats: m, l, _, _, o[32]
  float* ppart = part + ((size_t)(sp * 32 + bh) * LQ + q) * 36;
  if (quad == 0) { ppart[0] = m; ppart[1] = l; }
  *(f32x4*)(ppart + 4 + quad * 4)  = o0;
  *(f32x4*)(ppart + 20 + quad * 4) = o1;
}

// ---------------------------------------------------------------------------
// Wo -> bf16 hi/lo split (row-major [n][k], same as Wo).
// ---------------------------------------------------------------------------
__global__ __launch_bounds__(256) void wo_prep_kernel(
    const float* __restrict__ Wo, short* __restrict__ WoH, short* __restrict__ WoL)
{
  const int i = (blockIdx.x * 256 + threadIdx.x) * 4;
  const f32x4 v = *(const f32x4*)(Wo + i);
  s16x4 h, l;
  #pragma unroll
  for (int j = 0; j < 4; ++j) {
    h[j] = f2bf(v[j]);
    l[j] = f2bf(v[j] - bf2f(h[j]));
  }
  *(s16x4*)(WoH + i) = h;
  *(s16x4*)(WoL + i) = l;
}

// ---------------------------------------------------------------------------
// Fused combine + output GEMM via MFMA (hi/lo bf16 compensation).
// ---------------------------------------------------------------------------
__global__ __launch_bounds__(256) void out_kernel(
    const float* __restrict__ part, const short* __restrict__ WoH,
    const short* __restrict__ WoL, const float* __restrict__ bo,
    float* __restrict__ out)
{
  const int t = threadIdx.x;
  const int wv = t >> 6, lane = t & 63;
  const int lo16 = lane & 15, quad = lane >> 4;
  const int mt = blockIdx.x;                 // m-tile of 16 rows
  const size_t gq = (size_t)mt * 16 + lo16;  // ctx row for A fragment
  const int b = (int)(gq >> 10), qq = (int)(gq & (LQ - 1));

  // ---- A fragments (8 windows = 8 heads), combine SPLIT partials ----
  bf16x8 Ah[8], Al[8];
  #pragma unroll
  for (int win = 0; win < 8; ++win) {
    const size_t r = (size_t)(b * H_ + win) * LQ + qq;
    const float* p0 = part + r * 36;
    const float* p1 = part + (r + (size_t)B_ * H_ * LQ) * 36;
    const float m0 = p0[0], l0 = p0[1], m1 = p1[0], l1 = p1[1];
    const float mM = fmaxf(m0, m1);
    const float w0 = __builtin_amdgcn_exp2f(m0 - mM);
    const float w1 = __builtin_amdgcn_exp2f(m1 - mM);
    const float inv = 1.f / (w0 * l0 + w1 * l1);
    const f32x4 a0  = *(const f32x4*)(p0 + 4 + quad * 8);
    const f32x4 a0b = *(const f32x4*)(p0 + 8 + quad * 8);
    const f32x4 a1  = *(const f32x4*)(p1 + 4 + quad * 8);
    const f32x4 a1b = *(const f32x4*)(p1 + 8 + quad * 8);
    float c8[8];
    #pragma unroll
    for (int j = 0; j < 4; ++j) {
      c8[j]     = (w0 * a0[j]  + w1 * a1[j])  * inv;
      c8[4 + j] = (w0 * a0b[j] + w1 * a1b[j]) * inv;
    }
    #pragma unroll
    for (int j = 0; j < 8; ++j) {
      const short hi = f2bf(c8[j]);
      Ah[win][j] = hi;
      Al[win][j] = f2bf(c8[j] - bf2f(hi));
    }
  }

  // ---- 4 n-tiles of 16 cols each ----
  const int n0 = wv * 64;
  #pragma unroll
  for (int nt = 0; nt < 4; ++nt) {
    const int nb = n0 + nt * 16;
    const short* bh = WoH + (size_t)(nb + lo16) * HID_ + quad * 8;
    const short* bl = WoL + (size_t)(nb + lo16) * HID_ + quad * 8;
    const float bias = bo[nb + lo16];
    f32x4 acc = {bias, bias, bias, bias};
    #pragma unroll
    for (int win = 0; win < 8; ++win) {
      const bf16x8 Bh = *(const bf16x8*)(bh + win * 32);
      const bf16x8 Bl = *(const bf16x8*)(bl + win * 32);
      acc = __builtin_amdgcn_mfma_f32_16x16x32_bf16(Ah[win], Bh, acc, 0, 0, 0);
      acc = __builtin_amdgcn_mfma_f32_16x16x32_bf16(Al[win], Bh, acc, 0, 0, 0);
      acc = __builtin_amdgcn_mfma_f32_16x16x32_bf16(Ah[win], Bl, acc, 0, 0, 0);
    }
    #pragma unroll
    for (int r4 = 0; r4 < 4; ++r4)
      out[(size_t)(mt * 16 + quad * 4 + r4) * HID_ + nb + lo16] = acc[r4];
  }
}

// ---------------------------------------------------------------------------
extern "C" void kernel_launch(void* const* d_in, const int* in_sizes, int n_in,
                              void* d_out, int out_size, void* d_ws, size_t ws_size,
                              hipStream_t stream)
{
  const float* q_fp  = (const float*)d_in[0];
  const float* v_ret = (const float*)d_in[1];
  const float* pi    = (const float*)d_in[2];
  const float* Wq_s  = (const float*)d_in[3];
  const float* bq_s  = (const float*)d_in[4];
  const float* Wk_s  = (const float*)d_in[5];
  const float* bk_s  = (const float*)d_in[6];
  const float* Wq_w  = (const float*)d_in[7];
  const float* bq_w  = (const float*)d_in[8];
  const float* Wk_w  = (const float*)d_in[9];
  const float* bk_w  = (const float*)d_in[10];
  const float* Wv    = (const float*)d_in[11];
  const float* bv    = (const float*)d_in[12];
  const float* Wo    = (const float*)d_in[13];
  const float* bo    = (const float*)d_in[14];
  const float* wb    = (const float*)d_in[15];
  float* out = (float*)d_out;

  // ws: Qh 4MB | KV 12MB | kb 256KB | piP 32MB | part 9MB  (~57.3 MB)
  short* Qh   = (short*)d_ws;                     // 2,097,152 sh
  short* KV   = Qh + (size_t)2097152;             // 6,291,456 sh
  float* kbuf = (float*)(KV + (size_t)6291456);   //    65,536 fl
  float* piP  = kbuf + (size_t)65536;             // 8,388,608 fl
  float* part = piP + (size_t)8388608;            // 2,359,296 fl
  // WoH/WoL alias the piP region (dead after attn_kernel completes)
  short* WoH  = (short*)piP;                      //    65,536 sh
  short* WoL  = WoH + (size_t)65536;              //    65,536 sh

  proj_q_kernel<<<B_ * LQ, 256, 0, stream>>>(q_fp, Wq_s, bq_s, Wq_w, bq_w, wb, Qh);
  projk_pack_kernel<<<dim3(LK / 64, 32), 256, 0, stream>>>(
      v_ret, Wk_s, bk_s, Wk_w, bk_w, Wv, bv, wb, KV, kbuf);
  pi_prepack_kernel<<<8192, 256, 0, stream>>>(pi, piP);
  attn_kernel<<<(LQ / 64) * 32 * SPLIT, 256, 0, stream>>>(Qh, KV, kbuf, piP, part);
  wo_prep_kernel<<<64, 256, 0, stream>>>(Wo, WoH, WoL);
  out_kernel<<<(B_ * LQ) / 16, 256, 0, stream>>>(part, WoH, WoL, bo, out);
}